// Round 4
// baseline (794.174 us; speedup 1.0000x reference)
//
#include <hip/hip_runtime.h>

// ARMA GNN (T=1,K=1) x2 layers on MI355X — bucketed multisplit + LDS-accumulated gather.
// ZERO global atomics (round-3 lesson: device-scope atomics cost ~40ns each at the
// coherence point regardless of L2 residency; 6.4M of them = ~260us of the 455us).
//
// Pipeline (edge partition built once, reused by both layers):
//   P1  part_hist:    per-chunk LDS histogram over B=ceil(n/128) col-range buckets
//                     -> histg[bucket*NB + chunk]
//   S   3-kernel hierarchical exclusive scan of histg (flat, bucket-major) -> basee
//   P3  part_scatter: re-read edges; in-bucket rank via LDS cursor; write packed
//                     (lcol<<17 | row) int per edge -> srt (bucket-contiguous)
//   D   dinv:         per-bucket LDS histogram of local cols -> dinv=rsqrt(deg)
// Per layer:
//   proj:   p[i] = (h[i] @ W) * dinv[i]
//   gather: block per bucket; LDS acc[128][16]; per edge: broadcast packed load,
//           coalesced 64B p-row gather, 16 LDS float atomicAdds; fused finish
//           out[c] = relu(dinv[c]*acc + h[c]@V + b)  (register-staged: alias-safe)

#define WC 128          // bucket width (cols)
#define LG2WC 7
#define MAXB 1024       // max buckets (supports n up to 131072)
#define NBC 512         // partition chunks

__global__ void part_hist(const int* __restrict__ col, int* __restrict__ histg,
                          int E, int B, int chunk) {
    __shared__ int h[MAXB];
    int i = blockIdx.x, t = threadIdx.x;
    for (int j = t; j < B; j += 256) h[j] = 0;
    __syncthreads();
    int lo = i * chunk, hi = lo + chunk; if (hi > E) hi = E;
    for (int e = lo + t; e < hi; e += 256) {
        int c = __builtin_nontemporal_load(col + e);
        atomicAdd(&h[c >> LG2WC], 1);
    }
    __syncthreads();
    for (int j = t; j < B; j += 256) histg[(size_t)j * NBC + i] = h[j];
}

// ---- hierarchical exclusive scan over histg[0..m) -> basee ----
__global__ void scan_partial_kernel(const int* __restrict__ v, int* __restrict__ bsum, int m) {
    __shared__ int red[256];
    int blk = blockIdx.x, t = threadIdx.x;
    int base0 = blk * 1024;
    int s = 0;
    for (int q = t; q < 1024; q += 256) {
        int idx = base0 + q;
        if (idx < m) s += v[idx];
    }
    red[t] = s;
    __syncthreads();
    for (int o = 128; o > 0; o >>= 1) {
        if (t < o) red[t] += red[t + o];
        __syncthreads();
    }
    if (t == 0) bsum[blk] = red[0];
}

__global__ void scan_base_kernel(int* __restrict__ bsum, int nb) {
    __shared__ int s[512];
    int t = threadIdx.x;
    int v = (t < nb) ? bsum[t] : 0;
    s[t] = v;
    __syncthreads();
    for (int off = 1; off < 512; off <<= 1) {
        int u = 0;
        if (t >= off) u = s[t - off];
        __syncthreads();
        if (t >= off) s[t] += u;
        __syncthreads();
    }
    if (t < nb) bsum[t] = s[t] - v;  // exclusive
}

__global__ void scan_final_kernel(const int* __restrict__ v, const int* __restrict__ bbase,
                                  int* __restrict__ outp, int m) {
    __shared__ int tsum[256];
    int blk = blockIdx.x, t = threadIdx.x;
    int base0 = blk * 1024 + t * 4;
    int c[4];
#pragma unroll
    for (int k = 0; k < 4; k++) c[k] = (base0 + k < m) ? v[base0 + k] : 0;
    int s = c[0] + c[1] + c[2] + c[3];
    tsum[t] = s;
    __syncthreads();
    for (int off = 1; off < 256; off <<= 1) {
        int u = 0;
        if (t >= off) u = tsum[t - off];
        __syncthreads();
        if (t >= off) tsum[t] += u;
        __syncthreads();
    }
    int run = bbase[blk] + tsum[t] - s;
#pragma unroll
    for (int k = 0; k < 4; k++) {
        int idx = base0 + k;
        if (idx < m) { outp[idx] = run; run += c[k]; }
    }
}

__global__ void part_scatter(const int* __restrict__ row, const int* __restrict__ col,
                             const int* __restrict__ basee, int* __restrict__ srt,
                             int E, int B, int chunk) {
    __shared__ int cur[MAXB];
    int i = blockIdx.x, t = threadIdx.x;
    for (int j = t; j < B; j += 256) cur[j] = basee[(size_t)j * NBC + i];
    __syncthreads();
    int lo = i * chunk, hi = lo + chunk; if (hi > E) hi = E;
    for (int e = lo + t; e < hi; e += 256) {
        int c = __builtin_nontemporal_load(col + e);
        int r = __builtin_nontemporal_load(row + e);
        int j = c >> LG2WC;
        int pos = atomicAdd(&cur[j], 1);          // LDS atomic (fast)
        srt[pos] = r | ((c & (WC - 1)) << 17);    // row<2^17, lcol in bits 17..23
    }
}

__global__ void dinv_build_kernel(const int* __restrict__ basee, const int* __restrict__ srt,
                                  float* __restrict__ dinv, int E, int n, int B) {
    __shared__ int cnt[WC];
    int j = blockIdx.x, t = threadIdx.x;
    if (t < WC) cnt[t] = 0;
    __syncthreads();
    int s0 = basee[(size_t)j * NBC];
    int s1 = (j + 1 < B) ? basee[(size_t)(j + 1) * NBC] : E;
    for (int e = s0 + t; e < s1; e += 256) {
        int pk = __builtin_nontemporal_load(srt + e);
        atomicAdd(&cnt[pk >> 17], 1);
    }
    __syncthreads();
    if (t < WC) {
        int c = j * WC + t;
        if (c < n) {
            int d = cnt[t];
            dinv[c] = d > 0 ? rsqrtf((float)d) : 0.0f;
        }
    }
}

template <int FI>
__global__ void proj_kernel(const float* __restrict__ hin, const float* __restrict__ W,
                            const float* __restrict__ dinv, float* __restrict__ p, int n) {
    __shared__ float sW[FI * 16];
    for (int t = threadIdx.x; t < FI * 16; t += blockDim.x) sW[t] = W[t];
    __syncthreads();
    int i = blockIdx.x * blockDim.x + threadIdx.x;
    if (i >= n) return;
    float hi[FI];
    const float4* hr = (const float4*)(hin + (size_t)i * FI);
#pragma unroll
    for (int k = 0; k < FI / 4; k++) {
        float4 v = hr[k];
        hi[4 * k] = v.x; hi[4 * k + 1] = v.y; hi[4 * k + 2] = v.z; hi[4 * k + 3] = v.w;
    }
    float di = dinv[i];
    float outv[16];
#pragma unroll
    for (int f = 0; f < 16; f++) {
        float s = 0.0f;
#pragma unroll
        for (int k = 0; k < FI; k++) s += hi[k] * sW[k * 16 + f];
        outv[f] = s * di;
    }
    float4* pr = (float4*)(p + (size_t)i * 16);
#pragma unroll
    for (int q = 0; q < 4; q++)
        pr[q] = make_float4(outv[4 * q], outv[4 * q + 1], outv[4 * q + 2], outv[4 * q + 3]);
}

// One block per bucket. hin/out may alias (layer 2) -> register-stage finish + barrier.
template <int FI>
__global__ void gather_finish(const int* __restrict__ basee, const int* __restrict__ srt,
                              const float* __restrict__ p, const float* hin,
                              const float* __restrict__ V, const float* __restrict__ b,
                              const float* __restrict__ dinv, float* out,
                              int E, int n, int B) {
    __shared__ float acc[WC * 16];      // 8 KB
    __shared__ float sV[FI * 16];
    __shared__ float sb[16];
    int t = threadIdx.x;
    for (int q = t; q < FI * 16; q += 256) sV[q] = V[q];
    if (t < 16) sb[t] = b[t];
    for (int q = t; q < WC * 16; q += 256) acc[q] = 0.0f;
    __syncthreads();
    int j = blockIdx.x;
    int s0 = basee[(size_t)j * NBC];
    int s1 = (j + 1 < B) ? basee[(size_t)(j + 1) * NBC] : E;
    int g = t >> 4, f = t & 15;         // 16 groups x 16 feature lanes
    int e = s0 + g;
    for (; e + 16 < s1; e += 32) {      // unroll 2 for MLP on the srt->p chain
        int pk0 = srt[e];
        int pk1 = srt[e + 16];
        float v0 = p[(size_t)(pk0 & 0x1FFFF) * 16 + f];
        float v1 = p[(size_t)(pk1 & 0x1FFFF) * 16 + f];
        atomicAdd(&acc[((pk0 >> 17) << 4) + f], v0);
        atomicAdd(&acc[((pk1 >> 17) << 4) + f], v1);
    }
    for (; e < s1; e += 16) {
        int pk = srt[e];
        atomicAdd(&acc[((pk >> 17) << 4) + f], p[(size_t)(pk & 0x1FFFF) * 16 + f]);
    }
    __syncthreads();
    // finish: compute everything into registers first (alias-safe), then barrier, then write
    float res[(WC * 16) / 256];         // 8
#pragma unroll
    for (int q = 0; q < (WC * 16) / 256; q++) {
        int idx = t + q * 256;
        int lc = idx >> 4, ff = idx & 15;
        int c = j * WC + lc;
        float r_ = 0.0f;
        if (c < n) {
            const float* hr = hin + (size_t)c * FI;
            float hv = 0.0f;
#pragma unroll
            for (int k = 0; k < FI; k++) hv += hr[k] * sV[k * 16 + ff];
            r_ = sb[ff] + dinv[c] * acc[idx] + hv;
            r_ = r_ > 0.0f ? r_ : 0.0f;
        }
        res[q] = r_;
    }
    __syncthreads();                    // all hin reads complete before any out write
#pragma unroll
    for (int q = 0; q < (WC * 16) / 256; q++) {
        int idx = t + q * 256;
        int c = j * WC + (idx >> 4);
        if (c < n) out[(size_t)c * 16 + (idx & 15)] = res[q];
    }
}

extern "C" void kernel_launch(void* const* d_in, const int* in_sizes, int n_in,
                              void* d_out, int out_size, void* d_ws, size_t ws_size,
                              hipStream_t stream) {
    const float* x  = (const float*)d_in[0];
    const int*   ei = (const int*)d_in[1];
    const float* W1 = (const float*)d_in[2];
    const float* V1 = (const float*)d_in[3];
    const float* b1 = (const float*)d_in[4];
    const float* W2 = (const float*)d_in[5];
    const float* V2 = (const float*)d_in[6];
    const float* b2 = (const float*)d_in[7];

    const int n = in_sizes[0] / 8;       // 100000 nodes
    const int E = in_sizes[1] / 2;       // 3200000 edges
    const int* row = ei;                 // edge_index[0]
    const int* col = ei + E;             // edge_index[1]

    const int B = (n + WC - 1) / WC;     // 782 buckets
    const int m = B * NBC;               // hist table size
    const int chunk = (E + NBC - 1) / NBC;
    const int sbn = (m + 1023) / 1024;   // scan blocks (<=512 required)

    auto align = [](size_t v) { return (v + 255) / 256 * 256; };
    char* ws = (char*)d_ws;
    size_t off = 0;
    float* dinv  = (float*)(ws + off); off += align((size_t)n * 4);
    int*   histg = (int*)(ws + off);   off += align((size_t)m * 4);
    int*   basee = (int*)(ws + off);   off += align((size_t)m * 4);
    int*   bsum  = (int*)(ws + off);   off += align((size_t)sbn * 4);
    int*   srt   = (int*)(ws + off);   off += align((size_t)E * 4);
    float* p     = (float*)(ws + off); off += align((size_t)n * 16 * 4);
    float* out   = (float*)d_out;
    // ~23 MB total

    const int bs = 256;
    const int gbN = (n + bs - 1) / bs;

    // partition build (no global atomics anywhere)
    part_hist<<<NBC, bs, 0, stream>>>(col, histg, E, B, chunk);
    scan_partial_kernel<<<sbn, bs, 0, stream>>>(histg, bsum, m);
    scan_base_kernel<<<1, 512, 0, stream>>>(bsum, sbn);
    scan_final_kernel<<<sbn, bs, 0, stream>>>(histg, bsum, basee, m);
    part_scatter<<<NBC, bs, 0, stream>>>(row, col, basee, srt, E, B, chunk);
    dinv_build_kernel<<<B, bs, 0, stream>>>(basee, srt, dinv, E, n, B);

    // Layer 1 (FI=8): x -> d_out
    proj_kernel<8><<<gbN, bs, 0, stream>>>(x, W1, dinv, p, n);
    gather_finish<8><<<B, bs, 0, stream>>>(basee, srt, p, x, V1, b1, dinv, out, E, n, B);

    // Layer 2 (FI=16): d_out -> d_out
    proj_kernel<16><<<gbN, bs, 0, stream>>>(out, W2, dinv, p, n);
    gather_finish<16><<<B, bs, 0, stream>>>(basee, srt, p, out, V2, b2, dinv, out, E, n, B);
}

// Round 6
// 234.159 us; speedup vs baseline: 3.3916x; 3.3916x over previous
//
#include <hip/hip_runtime.h>

// ARMA GNN (T=1,K=1) x2 layers on MI355X — atomic-free CSR build + per-node gather.
// (Resubmission of round-5 kernel: container infra failure, no bench signal.)
//
// Round-4 lesson: bucketed LDS-accumulated gather starved parallelism (782 blocks,
// dependent chains, 22% occupancy) -> 349us. Round-3 per-node CSR gather (1.6M
// lanes, unroll-8) was ~90us. Round-3 lesson: global atomics cost ~40ns each.
// => Build the full per-col CSR with ZERO global atomics, gather round-3 style.
//
// Pipeline (built once, reused by both layers):
//   P1 part_hist:   per-chunk LDS histogram over B=782 col-buckets (width 128)
//   S  3-kernel hierarchical scan of histg[bucket][chunk] -> basee
//   P3 part_scatter: LDS cursors; srt_packed = (lcol<<17 | row), bucket-contiguous
//   LS local_sort:  per bucket: LDS col-histogram + scan -> per-col ptr, dinv,
//                   scatter rows to within-col slots -> srt2 (full CSR order)
// Per layer:
//   proj:   p[i] = (h[i] @ W) * dinv[i]          (p overlays dead srt_packed)
//   gather: 16 lanes/node, unroll-8 MLP on srt2->p chain, fused h@V+b+relu

#define WC 128          // bucket width (cols)
#define LG2WC 7
#define MAXB 1024       // max buckets (supports n up to 131072)
#define NBC 512         // partition chunks

__global__ void part_hist(const int* __restrict__ col, int* __restrict__ histg,
                          int E, int B, int chunk) {
    __shared__ int h[MAXB];
    int i = blockIdx.x, t = threadIdx.x;
    for (int j = t; j < B; j += 256) h[j] = 0;
    __syncthreads();
    int lo = i * chunk, hi = lo + chunk; if (hi > E) hi = E;
    for (int e = lo + t; e < hi; e += 256) {
        int c = __builtin_nontemporal_load(col + e);
        atomicAdd(&h[c >> LG2WC], 1);
    }
    __syncthreads();
    for (int j = t; j < B; j += 256) histg[(size_t)j * NBC + i] = h[j];
}

// ---- hierarchical exclusive scan over histg[0..m) -> basee ----
__global__ void scan_partial_kernel(const int* __restrict__ v, int* __restrict__ bsum, int m) {
    __shared__ int red[256];
    int blk = blockIdx.x, t = threadIdx.x;
    int base0 = blk * 1024;
    int s = 0;
    for (int q = t; q < 1024; q += 256) {
        int idx = base0 + q;
        if (idx < m) s += v[idx];
    }
    red[t] = s;
    __syncthreads();
    for (int o = 128; o > 0; o >>= 1) {
        if (t < o) red[t] += red[t + o];
        __syncthreads();
    }
    if (t == 0) bsum[blk] = red[0];
}

__global__ void scan_base_kernel(int* __restrict__ bsum, int nb) {
    __shared__ int s[512];
    int t = threadIdx.x;
    int v = (t < nb) ? bsum[t] : 0;
    s[t] = v;
    __syncthreads();
    for (int off = 1; off < 512; off <<= 1) {
        int u = 0;
        if (t >= off) u = s[t - off];
        __syncthreads();
        if (t >= off) s[t] += u;
        __syncthreads();
    }
    if (t < nb) bsum[t] = s[t] - v;  // exclusive
}

__global__ void scan_final_kernel(const int* __restrict__ v, const int* __restrict__ bbase,
                                  int* __restrict__ outp, int m) {
    __shared__ int tsum[256];
    int blk = blockIdx.x, t = threadIdx.x;
    int base0 = blk * 1024 + t * 4;
    int c[4];
#pragma unroll
    for (int k = 0; k < 4; k++) c[k] = (base0 + k < m) ? v[base0 + k] : 0;
    int s = c[0] + c[1] + c[2] + c[3];
    tsum[t] = s;
    __syncthreads();
    for (int off = 1; off < 256; off <<= 1) {
        int u = 0;
        if (t >= off) u = tsum[t - off];
        __syncthreads();
        if (t >= off) tsum[t] += u;
        __syncthreads();
    }
    int run = bbase[blk] + tsum[t] - s;
#pragma unroll
    for (int k = 0; k < 4; k++) {
        int idx = base0 + k;
        if (idx < m) { outp[idx] = run; run += c[k]; }
    }
}

__global__ void part_scatter(const int* __restrict__ row, const int* __restrict__ col,
                             const int* __restrict__ basee, int* __restrict__ srt,
                             int E, int B, int chunk) {
    __shared__ int cur[MAXB];
    int i = blockIdx.x, t = threadIdx.x;
    for (int j = t; j < B; j += 256) cur[j] = basee[(size_t)j * NBC + i];
    __syncthreads();
    int lo = i * chunk, hi = lo + chunk; if (hi > E) hi = E;
    for (int e = lo + t; e < hi; e += 256) {
        int c = __builtin_nontemporal_load(col + e);
        int r = __builtin_nontemporal_load(row + e);
        int j = c >> LG2WC;
        int pos = atomicAdd(&cur[j], 1);          // LDS atomic (fast)
        srt[pos] = r | ((c & (WC - 1)) << 17);    // row<2^17, lcol in bits 17..23
    }
}

// Per bucket: col-histogram + LDS scan -> per-col ptr & dinv; scatter rows into
// within-col slots (full counting sort). Write window = bucket range (~16KB).
__global__ void local_sort(const int* __restrict__ basee, const int* __restrict__ srt,
                           int* __restrict__ ptr, int* __restrict__ srt2,
                           float* __restrict__ dinv, int E, int n, int B) {
    __shared__ int cnt[WC];
    __shared__ int sc[WC];
    __shared__ int cur[WC];
    int j = blockIdx.x, t = threadIdx.x;
    if (t < WC) cnt[t] = 0;
    __syncthreads();
    int s0 = basee[(size_t)j * NBC];
    int s1 = (j + 1 < B) ? basee[(size_t)(j + 1) * NBC] : E;
    for (int e = s0 + t; e < s1; e += 256) {
        int pk = __builtin_nontemporal_load(srt + e);
        atomicAdd(&cnt[pk >> 17], 1);
    }
    __syncthreads();
    if (t < WC) sc[t] = cnt[t];
    __syncthreads();
    for (int off = 1; off < WC; off <<= 1) {
        int u = 0;
        if (t >= off && t < WC) u = sc[t - off];
        __syncthreads();
        if (t >= off && t < WC) sc[t] += u;
        __syncthreads();
    }
    if (t < WC) {
        int base = s0 + sc[t] - cnt[t];   // exclusive
        cur[t] = base;
        int c = j * WC + t;
        if (c < n) {
            ptr[c] = base;
            dinv[c] = cnt[t] > 0 ? rsqrtf((float)cnt[t]) : 0.0f;
        }
    }
    if (j == B - 1 && t == 0) ptr[n] = E;
    __syncthreads();
    for (int e = s0 + t; e < s1; e += 256) {
        int pk = __builtin_nontemporal_load(srt + e);
        int pos = atomicAdd(&cur[pk >> 17], 1);
        srt2[pos] = pk & 0x1FFFF;
    }
}

template <int FI>
__global__ void proj_kernel(const float* __restrict__ hin, const float* __restrict__ W,
                            const float* __restrict__ dinv, float* __restrict__ p, int n) {
    __shared__ float sW[FI * 16];
    for (int t = threadIdx.x; t < FI * 16; t += blockDim.x) sW[t] = W[t];
    __syncthreads();
    int i = blockIdx.x * blockDim.x + threadIdx.x;
    if (i >= n) return;
    float hi[FI];
    const float4* hr = (const float4*)(hin + (size_t)i * FI);
#pragma unroll
    for (int k = 0; k < FI / 4; k++) {
        float4 v = hr[k];
        hi[4 * k] = v.x; hi[4 * k + 1] = v.y; hi[4 * k + 2] = v.z; hi[4 * k + 3] = v.w;
    }
    float di = dinv[i];
    float outv[16];
#pragma unroll
    for (int f = 0; f < 16; f++) {
        float s = 0.0f;
#pragma unroll
        for (int k = 0; k < FI; k++) s += hi[k] * sW[k * 16 + f];
        outv[f] = s * di;
    }
    float4* pr = (float4*)(p + (size_t)i * 16);
#pragma unroll
    for (int q = 0; q < 4; q++)
        pr[q] = make_float4(outv[4 * q], outv[4 * q + 1], outv[4 * q + 2], outv[4 * q + 3]);
}

// 16 lanes per node; lane f owns feature f. Gathers are one 64B line per edge.
// hin/out may alias (layer 2): each group reads only its OWN h row, then writes it.
template <int FI>
__global__ void gather_finish_kernel(const int* __restrict__ ptr, const int* __restrict__ srt2,
                                     const float* __restrict__ p, const float* hin,
                                     const float* __restrict__ V, const float* __restrict__ b,
                                     const float* __restrict__ dinv, float* out, int n) {
    __shared__ float sV[FI * 16];
    __shared__ float sb[16];
    for (int t = threadIdx.x; t < FI * 16; t += blockDim.x) sV[t] = V[t];
    if (threadIdx.x < 16) sb[threadIdx.x] = b[threadIdx.x];
    __syncthreads();
    int g = blockIdx.x * (blockDim.x >> 4) + (threadIdx.x >> 4);
    int f = threadIdx.x & 15;
    if (g >= n) return;
    int s0 = ptr[g], s1 = ptr[g + 1];
    float acc = 0.0f;
    int e = s0;
    // unroll-by-8 for memory-level parallelism on the dependent srt2->p chain
    for (; e + 8 <= s1; e += 8) {
        int r[8];
#pragma unroll
        for (int q = 0; q < 8; q++) r[q] = __builtin_nontemporal_load(srt2 + e + q);
        float a[8];
#pragma unroll
        for (int q = 0; q < 8; q++) a[q] = p[(size_t)r[q] * 16 + f];
        acc += ((a[0] + a[1]) + (a[2] + a[3])) + ((a[4] + a[5]) + (a[6] + a[7]));
    }
    for (; e < s1; e++) acc += p[(size_t)__builtin_nontemporal_load(srt2 + e) * 16 + f];
    // fused finish: h@V + b + dinv*agg, relu
    float hv = 0.0f;
    const float* hrow = hin + (size_t)g * FI;
#pragma unroll
    for (int k = 0; k < FI; k++) hv += hrow[k] * sV[k * 16 + f];
    float res = sb[f] + dinv[g] * acc + hv;
    out[(size_t)g * 16 + f] = res > 0.0f ? res : 0.0f;
}

extern "C" void kernel_launch(void* const* d_in, const int* in_sizes, int n_in,
                              void* d_out, int out_size, void* d_ws, size_t ws_size,
                              hipStream_t stream) {
    const float* x  = (const float*)d_in[0];
    const int*   ei = (const int*)d_in[1];
    const float* W1 = (const float*)d_in[2];
    const float* V1 = (const float*)d_in[3];
    const float* b1 = (const float*)d_in[4];
    const float* W2 = (const float*)d_in[5];
    const float* V2 = (const float*)d_in[6];
    const float* b2 = (const float*)d_in[7];

    const int n = in_sizes[0] / 8;       // 100000 nodes
    const int E = in_sizes[1] / 2;       // 3200000 edges
    const int* row = ei;                 // edge_index[0]
    const int* col = ei + E;             // edge_index[1]

    const int B = (n + WC - 1) / WC;     // 782 buckets
    const int m = B * NBC;               // hist table size (~400K)
    const int chunk = (E + NBC - 1) / NBC;
    const int sbn = (m + 1023) / 1024;   // scan blocks (<=512 required)

    auto align = [](size_t v) { return (v + 255) / 256 * 256; };
    char* ws = (char*)d_ws;
    size_t off = 0;
    float* dinv  = (float*)(ws + off); off += align((size_t)n * 4);
    int*   ptr   = (int*)(ws + off);   off += align((size_t)(n + 1) * 4);
    int*   histg = (int*)(ws + off);   off += align((size_t)m * 4);
    int*   basee = (int*)(ws + off);   off += align((size_t)m * 4);
    int*   bsum  = (int*)(ws + off);   off += align((size_t)sbn * 4);
    // srt_packed is dead after local_sort; proj writes p over the same region.
    int*   srt   = (int*)(ws + off);
    float* p     = (float*)(ws + off); off += align((size_t)E * 4);  // E*4 >= n*16*4
    int*   srt2  = (int*)(ws + off);   off += align((size_t)E * 4);
    float* out   = (float*)d_out;
    // ~30 MB total

    const int bs = 256;
    const int gbN = (n + bs - 1) / bs;
    const int gbG = (n * 16 + bs - 1) / bs;  // gather: 16 lanes per node

    // CSR build (no global atomics anywhere)
    part_hist<<<NBC, bs, 0, stream>>>(col, histg, E, B, chunk);
    scan_partial_kernel<<<sbn, bs, 0, stream>>>(histg, bsum, m);
    scan_base_kernel<<<1, 512, 0, stream>>>(bsum, sbn);
    scan_final_kernel<<<sbn, bs, 0, stream>>>(histg, bsum, basee, m);
    part_scatter<<<NBC, bs, 0, stream>>>(row, col, basee, srt, E, B, chunk);
    local_sort<<<B, bs, 0, stream>>>(basee, srt, ptr, srt2, dinv, E, n, B);

    // Layer 1 (FI=8): x -> d_out   (proj overwrites srt region with p — srt is dead)
    proj_kernel<8><<<gbN, bs, 0, stream>>>(x, W1, dinv, p, n);
    gather_finish_kernel<8><<<gbG, bs, 0, stream>>>(ptr, srt2, p, x, V1, b1, dinv, out, n);

    // Layer 2 (FI=16): d_out -> d_out
    proj_kernel<16><<<gbN, bs, 0, stream>>>(out, W2, dinv, p, n);
    gather_finish_kernel<16><<<gbG, bs, 0, stream>>>(ptr, srt2, p, out, V2, b2, dinv, out, n);
}

// Round 7
// 221.363 us; speedup vs baseline: 3.5877x; 1.0578x over previous
//
#include <hip/hip_runtime.h>

// ARMA GNN (T=1,K=1) x2 layers on MI355X — chunk-major partition + per-node gather.
//
// Round-6 lesson: bucket-major part_scatter wrote ~8-edge segments interleaved
// from 512 blocks -> 6x partial-line write amplification (79MB for 12.8MB) at
// 18% occupancy -> 64us. Fix: every kernel writes only single-writer,
// L2-resident contiguous windows.
//
// Pipeline (built once, reused by both layers):
//   CS chunk_sort:  block i counting-sorts its 6250-edge chunk by bucket in LDS;
//                   writes srt CHUNK-MAJOR (own 25KB window, coalesced) +
//                   histg[i][j] counts + segst[i][j] segment starts (coalesced).
//   T  tot_kernel:  tot[j] = sum_i histg[i][j]   (coalesced across j)
//   S  scan1024:    exclusive scan of 782 bucket totals -> bucket_base
//   BS bucket_sort: per bucket: scan count row, copy 512 segments into LDS stage,
//                   col-histogram -> ptr/dinv, scatter to srt2 CSR slots (16KB win).
// Per layer:
//   proj:   p[i] = (h[i] @ W) * dinv[i]          (p overlays dead srt)
//   gather: 16 lanes/node, unroll-8 MLP on srt2->p chain, fused h@V+b+relu

#define WC 128          // bucket width (cols)
#define LG2WC 7
#define MAXB 1024       // padded bucket count (supports n up to 131072)
#define NBC 512         // partition chunks
#define SCAP 8192       // bucket_sort LDS stage capacity (mean 4096 + 64 sigma)

// Block i: counting-sort its chunk by bucket; chunk-major output.
__global__ void chunk_sort(const int* __restrict__ row, const int* __restrict__ col,
                           int* __restrict__ srt, int* __restrict__ histg,
                           int* __restrict__ segst, int E, int B, int chunkE) {
    __shared__ int hist[MAXB];
    __shared__ int cur[MAXB];
    __shared__ int tsum[256];
    int i = blockIdx.x, t = threadIdx.x;
    for (int j = t; j < MAXB; j += 256) hist[j] = 0;
    __syncthreads();
    int lo = i * chunkE, hi = lo + chunkE; if (hi > E) hi = E;
    for (int e = lo + t; e < hi; e += 256)
        atomicAdd(&hist[col[e] >> LG2WC], 1);   // plain load: keep chunk L2-hot
    __syncthreads();
    // exclusive scan hist[0..MAXB) -> cur (4 elems/thread + Hillis-Steele)
    int b0 = t * 4;
    int c0 = hist[b0], c1 = hist[b0 + 1], c2 = hist[b0 + 2], c3 = hist[b0 + 3];
    int s = c0 + c1 + c2 + c3;
    tsum[t] = s;
    __syncthreads();
    for (int off = 1; off < 256; off <<= 1) {
        int u = 0;
        if (t >= off) u = tsum[t - off];
        __syncthreads();
        if (t >= off) tsum[t] += u;
        __syncthreads();
    }
    int run = tsum[t] - s;
    cur[b0] = run; run += c0;
    cur[b0 + 1] = run; run += c1;
    cur[b0 + 2] = run; run += c2;
    cur[b0 + 3] = run;
    __syncthreads();
    // write tables (chunk-major, coalesced)
    for (int j = t; j < B; j += 256) {
        histg[(size_t)i * B + j] = hist[j];
        segst[(size_t)i * B + j] = cur[j];
    }
    __syncthreads();
    // pass 2: re-read (L2-hot) and scatter into own window [lo,hi)
    for (int e = lo + t; e < hi; e += 256) {
        int c = col[e];
        int r = row[e];
        int pos = lo + atomicAdd(&cur[c >> LG2WC], 1);   // LDS cursor
        srt[pos] = ((c & (WC - 1)) << 17) | r;           // row<2^17, lcol bits 17..23
    }
}

__global__ void tot_kernel(const int* __restrict__ histg, int* __restrict__ tot, int B) {
    int j = blockIdx.x * blockDim.x + threadIdx.x;
    if (j >= B) return;
    int s = 0;
    for (int i = 0; i < NBC; i++) s += histg[(size_t)i * B + j];  // coalesced across j
    tot[j] = s;
}

__global__ void scan1024_kernel(const int* __restrict__ tot, int* __restrict__ base, int B) {
    __shared__ int s[1024];
    int t = threadIdx.x;
    int v = (t < B) ? tot[t] : 0;
    s[t] = v;
    __syncthreads();
    for (int off = 1; off < 1024; off <<= 1) {
        int u = 0;
        if (t >= off) u = s[t - off];
        __syncthreads();
        if (t >= off) s[t] += u;
        __syncthreads();
    }
    if (t < B) base[t] = s[t] - v;  // exclusive
}

// Per bucket: gather 512 segments (LDS stage), col-sort -> srt2 CSR + ptr + dinv.
__global__ void bucket_sort(const int* __restrict__ srt, const int* __restrict__ histg,
                            const int* __restrict__ segst, const int* __restrict__ bbase,
                            int* __restrict__ ptr, int* __restrict__ srt2,
                            float* __restrict__ dinv, int E, int n, int B, int chunkE) {
    __shared__ int hrow[NBC];
    __shared__ int srow[NBC];
    __shared__ int spref[NBC];
    __shared__ int stage[SCAP];
    __shared__ int tsum[256];
    __shared__ int cnt[WC], colb[WC], ccur[WC];
    __shared__ int Ssh;
    int j = blockIdx.x, t = threadIdx.x;
    for (int i = t; i < NBC; i += 256) {
        hrow[i] = histg[(size_t)i * B + j];   // strided, L2-resident table
        srow[i] = segst[(size_t)i * B + j];
    }
    if (t < WC) cnt[t] = 0;
    __syncthreads();
    // exclusive scan hrow[0..512) -> spref (2 elems/thread)
    int b0 = t * 2;
    int c0 = hrow[b0], c1 = hrow[b0 + 1];
    int s = c0 + c1;
    tsum[t] = s;
    __syncthreads();
    for (int off = 1; off < 256; off <<= 1) {
        int u = 0;
        if (t >= off) u = tsum[t - off];
        __syncthreads();
        if (t >= off) tsum[t] += u;
        __syncthreads();
    }
    int run = tsum[t] - s;
    spref[b0] = run;
    spref[b0 + 1] = run + c0;
    if (t == 255) Ssh = tsum[255];
    __syncthreads();
    int S = Ssh;                 // bucket size (block-uniform)
    int gbase = bbase[j];
    bool fits = (S <= SCAP);     // uniform branch
    if (fits) {
        for (int i = t; i < NBC; i += 256) {
            int src = i * chunkE + srow[i];
            int dst = spref[i];
            int len = hrow[i];
            for (int q = 0; q < len; q++) stage[dst + q] = srt[src + q];
        }
        __syncthreads();
        for (int e = t; e < S; e += 256) atomicAdd(&cnt[stage[e] >> 17], 1);
    } else {
        for (int i = t; i < NBC; i += 256) {
            int src = i * chunkE + srow[i];
            int len = hrow[i];
            for (int q = 0; q < len; q++) atomicAdd(&cnt[srt[src + q] >> 17], 1);
        }
    }
    __syncthreads();
    // scan cnt[0..128) -> colb; emit ptr/dinv; init cursors
    if (t < WC) colb[t] = cnt[t];
    __syncthreads();
    for (int off = 1; off < WC; off <<= 1) {
        int u = 0;
        if (t >= off && t < WC) u = colb[t - off];
        __syncthreads();
        if (t >= off && t < WC) colb[t] += u;
        __syncthreads();
    }
    if (t < WC) {
        int excl = colb[t] - cnt[t];
        int c = j * WC + t;
        ccur[t] = gbase + excl;
        if (c < n) {
            ptr[c] = gbase + excl;
            dinv[c] = cnt[t] > 0 ? rsqrtf((float)cnt[t]) : 0.0f;
        }
    }
    if (j == B - 1 && t == 0) ptr[n] = E;
    __syncthreads();
    if (fits) {
        for (int e = t; e < S; e += 256) {
            int pk = stage[e];
            int pos = atomicAdd(&ccur[pk >> 17], 1);
            srt2[pos] = pk & 0x1FFFF;
        }
    } else {
        for (int i = t; i < NBC; i += 256) {
            int src = i * chunkE + srow[i];
            int len = hrow[i];
            for (int q = 0; q < len; q++) {
                int pk = srt[src + q];
                int pos = atomicAdd(&ccur[pk >> 17], 1);
                srt2[pos] = pk & 0x1FFFF;
            }
        }
    }
}

template <int FI>
__global__ void proj_kernel(const float* __restrict__ hin, const float* __restrict__ W,
                            const float* __restrict__ dinv, float* __restrict__ p, int n) {
    __shared__ float sW[FI * 16];
    for (int t = threadIdx.x; t < FI * 16; t += blockDim.x) sW[t] = W[t];
    __syncthreads();
    int i = blockIdx.x * blockDim.x + threadIdx.x;
    if (i >= n) return;
    float hi[FI];
    const float4* hr = (const float4*)(hin + (size_t)i * FI);
#pragma unroll
    for (int k = 0; k < FI / 4; k++) {
        float4 v = hr[k];
        hi[4 * k] = v.x; hi[4 * k + 1] = v.y; hi[4 * k + 2] = v.z; hi[4 * k + 3] = v.w;
    }
    float di = dinv[i];
    float outv[16];
#pragma unroll
    for (int f = 0; f < 16; f++) {
        float s = 0.0f;
#pragma unroll
        for (int k = 0; k < FI; k++) s += hi[k] * sW[k * 16 + f];
        outv[f] = s * di;
    }
    float4* pr = (float4*)(p + (size_t)i * 16);
#pragma unroll
    for (int q = 0; q < 4; q++)
        pr[q] = make_float4(outv[4 * q], outv[4 * q + 1], outv[4 * q + 2], outv[4 * q + 3]);
}

// 16 lanes per node; lane f owns feature f. Gathers are one 64B line per edge.
// hin/out may alias (layer 2): each group reads only its OWN h row, then writes it.
template <int FI>
__global__ void gather_finish_kernel(const int* __restrict__ ptr, const int* __restrict__ srt2,
                                     const float* __restrict__ p, const float* hin,
                                     const float* __restrict__ V, const float* __restrict__ b,
                                     const float* __restrict__ dinv, float* out, int n) {
    __shared__ float sV[FI * 16];
    __shared__ float sb[16];
    for (int t = threadIdx.x; t < FI * 16; t += blockDim.x) sV[t] = V[t];
    if (threadIdx.x < 16) sb[threadIdx.x] = b[threadIdx.x];
    __syncthreads();
    int g = blockIdx.x * (blockDim.x >> 4) + (threadIdx.x >> 4);
    int f = threadIdx.x & 15;
    if (g >= n) return;
    int s0 = ptr[g], s1 = ptr[g + 1];
    float acc = 0.0f;
    int e = s0;
    // unroll-by-8 for memory-level parallelism on the dependent srt2->p chain
    for (; e + 8 <= s1; e += 8) {
        int r[8];
#pragma unroll
        for (int q = 0; q < 8; q++) r[q] = __builtin_nontemporal_load(srt2 + e + q);
        float a[8];
#pragma unroll
        for (int q = 0; q < 8; q++) a[q] = p[(size_t)r[q] * 16 + f];
        acc += ((a[0] + a[1]) + (a[2] + a[3])) + ((a[4] + a[5]) + (a[6] + a[7]));
    }
    for (; e < s1; e++) acc += p[(size_t)__builtin_nontemporal_load(srt2 + e) * 16 + f];
    // fused finish: h@V + b + dinv*agg, relu
    float hv = 0.0f;
    const float* hrow = hin + (size_t)g * FI;
#pragma unroll
    for (int k = 0; k < FI; k++) hv += hrow[k] * sV[k * 16 + f];
    float res = sb[f] + dinv[g] * acc + hv;
    out[(size_t)g * 16 + f] = res > 0.0f ? res : 0.0f;
}

extern "C" void kernel_launch(void* const* d_in, const int* in_sizes, int n_in,
                              void* d_out, int out_size, void* d_ws, size_t ws_size,
                              hipStream_t stream) {
    const float* x  = (const float*)d_in[0];
    const int*   ei = (const int*)d_in[1];
    const float* W1 = (const float*)d_in[2];
    const float* V1 = (const float*)d_in[3];
    const float* b1 = (const float*)d_in[4];
    const float* W2 = (const float*)d_in[5];
    const float* V2 = (const float*)d_in[6];
    const float* b2 = (const float*)d_in[7];

    const int n = in_sizes[0] / 8;       // 100000 nodes
    const int E = in_sizes[1] / 2;       // 3200000 edges
    const int* row = ei;                 // edge_index[0]
    const int* col = ei + E;             // edge_index[1]

    const int B = (n + WC - 1) / WC;     // 782 buckets
    const int chunkE = (E + NBC - 1) / NBC;  // 6250

    auto align = [](size_t v) { return (v + 255) / 256 * 256; };
    char* ws = (char*)d_ws;
    size_t off = 0;
    float* dinv  = (float*)(ws + off); off += align((size_t)n * 4);
    int*   ptr   = (int*)(ws + off);   off += align((size_t)(n + 1) * 4);
    int*   histg = (int*)(ws + off);   off += align((size_t)NBC * B * 4);
    int*   segst = (int*)(ws + off);   off += align((size_t)NBC * B * 4);
    int*   tot   = (int*)(ws + off);   off += align((size_t)B * 4);
    int*   bbase = (int*)(ws + off);   off += align((size_t)B * 4);
    // srt is dead after bucket_sort; proj writes p over the same region.
    int*   srt   = (int*)(ws + off);
    float* p     = (float*)(ws + off); off += align((size_t)E * 4);  // E*4 >= n*16*4
    int*   srt2  = (int*)(ws + off);   off += align((size_t)E * 4);
    float* out   = (float*)d_out;
    // ~30 MB total

    const int bs = 256;
    const int gbN = (n + bs - 1) / bs;
    const int gbG = (n * 16 + bs - 1) / bs;  // gather: 16 lanes per node

    // CSR build (no global atomics; all writes single-writer L2-resident windows)
    chunk_sort<<<NBC, bs, 0, stream>>>(row, col, srt, histg, segst, E, B, chunkE);
    tot_kernel<<<(B + bs - 1) / bs, bs, 0, stream>>>(histg, tot, B);
    scan1024_kernel<<<1, 1024, 0, stream>>>(tot, bbase, B);
    bucket_sort<<<B, bs, 0, stream>>>(srt, histg, segst, bbase, ptr, srt2, dinv, E, n, B, chunkE);

    // Layer 1 (FI=8): x -> d_out   (proj overwrites srt region with p — srt is dead)
    proj_kernel<8><<<gbN, bs, 0, stream>>>(x, W1, dinv, p, n);
    gather_finish_kernel<8><<<gbG, bs, 0, stream>>>(ptr, srt2, p, x, V1, b1, dinv, out, n);

    // Layer 2 (FI=16): d_out -> d_out
    proj_kernel<16><<<gbN, bs, 0, stream>>>(out, W2, dinv, p, n);
    gather_finish_kernel<16><<<gbG, bs, 0, stream>>>(ptr, srt2, p, out, V2, b2, dinv, out, n);
}

// Round 8
// 190.855 us; speedup vs baseline: 4.1611x; 1.1599x over previous
//
#include <hip/hip_runtime.h>

// ARMA GNN (T=1,K=1) x2 layers on MI355X — chunk-major partition + bf16-packed gather.
//
// Round-7 lesson: gather FETCH=123MB vs 26MB ideal — p (6.4MB of 64B rows, random
// row access) doesn't fit the 4MiB per-XCD L2 -> ~16x re-fetch. Fix: pack p as
// bf16x2 (row=32B, p=3.2MB < L2/XCD) so gathers become L2 hits; 8 lanes/node,
// 2 features/lane, fp32 accumulation (only the summand is bf16-rounded).
//
// Pipeline (built once, reused by both layers):
//   CS chunk_sort:  block i counting-sorts its 6250-edge chunk by bucket in LDS;
//                   writes srt CHUNK-MAJOR (own 25KB window) + histg/segst tables.
//   T  tot_kernel:  tot[j] = sum_i histg[i][j]
//   S  scan1024:    exclusive scan of 782 bucket totals -> bucket_base
//   BS bucket_sort: per bucket: scan count row, copy segments into LDS stage,
//                   col-histogram -> ptr/dinv, scatter to srt2 CSR slots.
// Per layer:
//   proj:   p[i] = pack_bf16x2((h[i] @ W) * dinv[i])   (p overlays dead srt)
//   gather: 8 lanes/node, unroll-8, fused h@V+b+relu, fp32 out.

#define WC 128          // bucket width (cols)
#define LG2WC 7
#define MAXB 1024       // padded bucket count (supports n up to 131072)
#define NBC 512         // partition chunks
#define SCAP 8192       // bucket_sort LDS stage capacity

__device__ inline unsigned bf16rte(float x) {
    unsigned u = __float_as_uint(x);
    return (u + 0x7FFFu + ((u >> 16) & 1u)) >> 16;
}

// Block i: counting-sort its chunk by bucket; chunk-major output.
__global__ void chunk_sort(const int* __restrict__ row, const int* __restrict__ col,
                           int* __restrict__ srt, int* __restrict__ histg,
                           int* __restrict__ segst, int E, int B, int chunkE) {
    __shared__ int hist[MAXB];
    __shared__ int cur[MAXB];
    __shared__ int tsum[256];
    int i = blockIdx.x, t = threadIdx.x;
    for (int j = t; j < MAXB; j += 256) hist[j] = 0;
    __syncthreads();
    int lo = i * chunkE, hi = lo + chunkE; if (hi > E) hi = E;
    for (int e = lo + t; e < hi; e += 256)
        atomicAdd(&hist[col[e] >> LG2WC], 1);   // plain load: keep chunk L2-hot
    __syncthreads();
    // exclusive scan hist[0..MAXB) -> cur (4 elems/thread + Hillis-Steele)
    int b0 = t * 4;
    int c0 = hist[b0], c1 = hist[b0 + 1], c2 = hist[b0 + 2], c3 = hist[b0 + 3];
    int s = c0 + c1 + c2 + c3;
    tsum[t] = s;
    __syncthreads();
    for (int off = 1; off < 256; off <<= 1) {
        int u = 0;
        if (t >= off) u = tsum[t - off];
        __syncthreads();
        if (t >= off) tsum[t] += u;
        __syncthreads();
    }
    int run = tsum[t] - s;
    cur[b0] = run; run += c0;
    cur[b0 + 1] = run; run += c1;
    cur[b0 + 2] = run; run += c2;
    cur[b0 + 3] = run;
    __syncthreads();
    // write tables (chunk-major, coalesced)
    for (int j = t; j < B; j += 256) {
        histg[(size_t)i * B + j] = hist[j];
        segst[(size_t)i * B + j] = cur[j];
    }
    __syncthreads();
    // pass 2: re-read (L2-hot) and scatter into own window [lo,hi)
    for (int e = lo + t; e < hi; e += 256) {
        int c = col[e];
        int r = row[e];
        int pos = lo + atomicAdd(&cur[c >> LG2WC], 1);   // LDS cursor
        srt[pos] = ((c & (WC - 1)) << 17) | r;           // row<2^17, lcol bits 17..23
    }
}

__global__ void tot_kernel(const int* __restrict__ histg, int* __restrict__ tot, int B) {
    int j = blockIdx.x * blockDim.x + threadIdx.x;
    if (j >= B) return;
    int s = 0;
    for (int i = 0; i < NBC; i++) s += histg[(size_t)i * B + j];  // coalesced across j
    tot[j] = s;
}

__global__ void scan1024_kernel(const int* __restrict__ tot, int* __restrict__ base, int B) {
    __shared__ int s[1024];
    int t = threadIdx.x;
    int v = (t < B) ? tot[t] : 0;
    s[t] = v;
    __syncthreads();
    for (int off = 1; off < 1024; off <<= 1) {
        int u = 0;
        if (t >= off) u = s[t - off];
        __syncthreads();
        if (t >= off) s[t] += u;
        __syncthreads();
    }
    if (t < B) base[t] = s[t] - v;  // exclusive
}

// Per bucket: gather 512 segments (LDS stage), col-sort -> srt2 CSR + ptr + dinv.
__global__ void bucket_sort(const int* __restrict__ srt, const int* __restrict__ histg,
                            const int* __restrict__ segst, const int* __restrict__ bbase,
                            int* __restrict__ ptr, int* __restrict__ srt2,
                            float* __restrict__ dinv, int E, int n, int B, int chunkE) {
    __shared__ int hrow[NBC];
    __shared__ int srow[NBC];
    __shared__ int spref[NBC];
    __shared__ int stage[SCAP];
    __shared__ int tsum[256];
    __shared__ int cnt[WC], colb[WC], ccur[WC];
    __shared__ int Ssh;
    int j = blockIdx.x, t = threadIdx.x;
    for (int i = t; i < NBC; i += 256) {
        hrow[i] = histg[(size_t)i * B + j];   // strided, L2-resident table
        srow[i] = segst[(size_t)i * B + j];
    }
    if (t < WC) cnt[t] = 0;
    __syncthreads();
    // exclusive scan hrow[0..512) -> spref (2 elems/thread)
    int b0 = t * 2;
    int c0 = hrow[b0], c1 = hrow[b0 + 1];
    int s = c0 + c1;
    tsum[t] = s;
    __syncthreads();
    for (int off = 1; off < 256; off <<= 1) {
        int u = 0;
        if (t >= off) u = tsum[t - off];
        __syncthreads();
        if (t >= off) tsum[t] += u;
        __syncthreads();
    }
    int run = tsum[t] - s;
    spref[b0] = run;
    spref[b0 + 1] = run + c0;
    if (t == 255) Ssh = tsum[255];
    __syncthreads();
    int S = Ssh;                 // bucket size (block-uniform)
    int gbase = bbase[j];
    bool fits = (S <= SCAP);     // uniform branch
    if (fits) {
        for (int i = t; i < NBC; i += 256) {
            int src = i * chunkE + srow[i];
            int dst = spref[i];
            int len = hrow[i];
            for (int q = 0; q < len; q++) stage[dst + q] = srt[src + q];
        }
        __syncthreads();
        for (int e = t; e < S; e += 256) atomicAdd(&cnt[stage[e] >> 17], 1);
    } else {
        for (int i = t; i < NBC; i += 256) {
            int src = i * chunkE + srow[i];
            int len = hrow[i];
            for (int q = 0; q < len; q++) atomicAdd(&cnt[srt[src + q] >> 17], 1);
        }
    }
    __syncthreads();
    // scan cnt[0..128) -> colb; emit ptr/dinv; init cursors
    if (t < WC) colb[t] = cnt[t];
    __syncthreads();
    for (int off = 1; off < WC; off <<= 1) {
        int u = 0;
        if (t >= off && t < WC) u = colb[t - off];
        __syncthreads();
        if (t >= off && t < WC) colb[t] += u;
        __syncthreads();
    }
    if (t < WC) {
        int excl = colb[t] - cnt[t];
        int c = j * WC + t;
        ccur[t] = gbase + excl;
        if (c < n) {
            ptr[c] = gbase + excl;
            dinv[c] = cnt[t] > 0 ? rsqrtf((float)cnt[t]) : 0.0f;
        }
    }
    if (j == B - 1 && t == 0) ptr[n] = E;
    __syncthreads();
    if (fits) {
        for (int e = t; e < S; e += 256) {
            int pk = stage[e];
            int pos = atomicAdd(&ccur[pk >> 17], 1);
            srt2[pos] = pk & 0x1FFFF;
        }
    } else {
        for (int i = t; i < NBC; i += 256) {
            int src = i * chunkE + srow[i];
            int len = hrow[i];
            for (int q = 0; q < len; q++) {
                int pk = srt[src + q];
                int pos = atomicAdd(&ccur[pk >> 17], 1);
                srt2[pos] = pk & 0x1FFFF;
            }
        }
    }
}

// p row = 8 uint32 (16 bf16) = 32 B.
template <int FI>
__global__ void proj_kernel(const float* __restrict__ hin, const float* __restrict__ W,
                            const float* __restrict__ dinv, unsigned* __restrict__ p, int n) {
    __shared__ float sW[FI * 16];
    for (int t = threadIdx.x; t < FI * 16; t += blockDim.x) sW[t] = W[t];
    __syncthreads();
    int i = blockIdx.x * blockDim.x + threadIdx.x;
    if (i >= n) return;
    float hi[FI];
    const float4* hr = (const float4*)(hin + (size_t)i * FI);
#pragma unroll
    for (int k = 0; k < FI / 4; k++) {
        float4 v = hr[k];
        hi[4 * k] = v.x; hi[4 * k + 1] = v.y; hi[4 * k + 2] = v.z; hi[4 * k + 3] = v.w;
    }
    float di = dinv[i];
    float outv[16];
#pragma unroll
    for (int f = 0; f < 16; f++) {
        float s = 0.0f;
#pragma unroll
        for (int k = 0; k < FI; k++) s += hi[k] * sW[k * 16 + f];
        outv[f] = s * di;
    }
    uint4 u0, u1;
    u0.x = bf16rte(outv[0])  | (bf16rte(outv[1])  << 16);
    u0.y = bf16rte(outv[2])  | (bf16rte(outv[3])  << 16);
    u0.z = bf16rte(outv[4])  | (bf16rte(outv[5])  << 16);
    u0.w = bf16rte(outv[6])  | (bf16rte(outv[7])  << 16);
    u1.x = bf16rte(outv[8])  | (bf16rte(outv[9])  << 16);
    u1.y = bf16rte(outv[10]) | (bf16rte(outv[11]) << 16);
    u1.z = bf16rte(outv[12]) | (bf16rte(outv[13]) << 16);
    u1.w = bf16rte(outv[14]) | (bf16rte(outv[15]) << 16);
    uint4* pr = (uint4*)(p + (size_t)i * 8);
    pr[0] = u0;
    pr[1] = u1;
}

// 8 lanes per node; lane f2 owns features {2*f2, 2*f2+1}. One 4B uint per lane
// per edge (32 B/group/edge); fp32 accumulate; fused h@V+b+relu; float2 store.
// hin/out may alias (layer 2): all lanes of a group read only their OWN h row
// (wave-lockstep: reads precede stores in program order).
template <int FI>
__global__ void gather_finish_kernel(const int* __restrict__ ptr, const int* __restrict__ srt2,
                                     const unsigned* __restrict__ p, const float* hin,
                                     const float* __restrict__ V, const float* __restrict__ b,
                                     const float* __restrict__ dinv, float* out, int n) {
    __shared__ float sV[FI * 16];
    __shared__ float sb[16];
    for (int t = threadIdx.x; t < FI * 16; t += blockDim.x) sV[t] = V[t];
    if (threadIdx.x < 16) sb[threadIdx.x] = b[threadIdx.x];
    __syncthreads();
    int g = blockIdx.x * (blockDim.x >> 3) + (threadIdx.x >> 3);
    int f2 = threadIdx.x & 7;
    if (g >= n) return;
    int s0 = ptr[g], s1 = ptr[g + 1];
    float a0 = 0.0f, a1 = 0.0f;
    int e = s0;
    for (; e + 8 <= s1; e += 8) {
        int r[8];
#pragma unroll
        for (int q = 0; q < 8; q++) r[q] = __builtin_nontemporal_load(srt2 + e + q);
        unsigned u[8];
#pragma unroll
        for (int q = 0; q < 8; q++) u[q] = p[(size_t)r[q] * 8 + f2];
#pragma unroll
        for (int q = 0; q < 8; q++) {
            a0 += __uint_as_float(u[q] << 16);
            a1 += __uint_as_float(u[q] & 0xFFFF0000u);
        }
    }
    for (; e < s1; e++) {
        unsigned u = p[(size_t)__builtin_nontemporal_load(srt2 + e) * 8 + f2];
        a0 += __uint_as_float(u << 16);
        a1 += __uint_as_float(u & 0xFFFF0000u);
    }
    // fused finish: h@V + b + dinv*agg, relu
    int f0 = 2 * f2;
    float hv0 = 0.0f, hv1 = 0.0f;
    const float* hrow = hin + (size_t)g * FI;
#pragma unroll
    for (int k = 0; k < FI; k++) {
        float hk = hrow[k];
        hv0 += hk * sV[k * 16 + f0];
        hv1 += hk * sV[k * 16 + f0 + 1];
    }
    float di = dinv[g];
    float r0 = sb[f0] + di * a0 + hv0;
    float r1 = sb[f0 + 1] + di * a1 + hv1;
    r0 = r0 > 0.0f ? r0 : 0.0f;
    r1 = r1 > 0.0f ? r1 : 0.0f;
    *(float2*)(out + (size_t)g * 16 + f0) = make_float2(r0, r1);
}

extern "C" void kernel_launch(void* const* d_in, const int* in_sizes, int n_in,
                              void* d_out, int out_size, void* d_ws, size_t ws_size,
                              hipStream_t stream) {
    const float* x  = (const float*)d_in[0];
    const int*   ei = (const int*)d_in[1];
    const float* W1 = (const float*)d_in[2];
    const float* V1 = (const float*)d_in[3];
    const float* b1 = (const float*)d_in[4];
    const float* W2 = (const float*)d_in[5];
    const float* V2 = (const float*)d_in[6];
    const float* b2 = (const float*)d_in[7];

    const int n = in_sizes[0] / 8;       // 100000 nodes
    const int E = in_sizes[1] / 2;       // 3200000 edges
    const int* row = ei;                 // edge_index[0]
    const int* col = ei + E;             // edge_index[1]

    const int B = (n + WC - 1) / WC;     // 782 buckets
    const int chunkE = (E + NBC - 1) / NBC;  // 6250

    auto align = [](size_t v) { return (v + 255) / 256 * 256; };
    char* ws = (char*)d_ws;
    size_t off = 0;
    float* dinv  = (float*)(ws + off); off += align((size_t)n * 4);
    int*   ptr   = (int*)(ws + off);   off += align((size_t)(n + 1) * 4);
    int*   histg = (int*)(ws + off);   off += align((size_t)NBC * B * 4);
    int*   segst = (int*)(ws + off);   off += align((size_t)NBC * B * 4);
    int*   tot   = (int*)(ws + off);   off += align((size_t)B * 4);
    int*   bbase = (int*)(ws + off);   off += align((size_t)B * 4);
    // srt is dead after bucket_sort; proj writes packed p over the same region.
    int*      srt = (int*)(ws + off);
    unsigned* p   = (unsigned*)(ws + off); off += align((size_t)E * 4);  // E*4 >= n*8*4
    int*      srt2 = (int*)(ws + off);     off += align((size_t)E * 4);
    float* out = (float*)d_out;
    // ~30 MB total

    const int bs = 256;
    const int gbN = (n + bs - 1) / bs;
    const int gbG = (n * 8 + bs - 1) / bs;   // gather: 8 lanes per node

    // CSR build (no global atomics; all writes single-writer L2-resident windows)
    chunk_sort<<<NBC, bs, 0, stream>>>(row, col, srt, histg, segst, E, B, chunkE);
    tot_kernel<<<(B + bs - 1) / bs, bs, 0, stream>>>(histg, tot, B);
    scan1024_kernel<<<1, 1024, 0, stream>>>(tot, bbase, B);
    bucket_sort<<<B, bs, 0, stream>>>(srt, histg, segst, bbase, ptr, srt2, dinv, E, n, B, chunkE);

    // Layer 1 (FI=8): x -> d_out   (proj overwrites srt region with p — srt is dead)
    proj_kernel<8><<<gbN, bs, 0, stream>>>(x, W1, dinv, p, n);
    gather_finish_kernel<8><<<gbG, bs, 0, stream>>>(ptr, srt2, p, x, V1, b1, dinv, out, n);

    // Layer 2 (FI=16): d_out -> d_out
    proj_kernel<16><<<gbN, bs, 0, stream>>>(out, W2, dinv, p, n);
    gather_finish_kernel<16><<<gbG, bs, 0, stream>>>(ptr, srt2, p, out, V2, b2, dinv, out, n);
}

// Round 9
// 164.044 us; speedup vs baseline: 4.8412x; 1.1634x over previous
//
#include <hip/hip_runtime.h>

// ARMA GNN (T=1,K=1) x2 layers on MI355X — chunk-major partition + bf16-packed
// wide-load gather.
//
// Round-8 lessons: (a) gather was latency-SLOT bound (51.2M 4B lane-loads);
// fix: 2 lanes/node, uint4 loads -> 12.8M lane-loads, same bytes.
// (b) bucket_sort FETCH=44MB for 12.8MB srt: 32B segments straddle lines;
// fix: NBC 512->256 (64B segments). (c) tot_kernel had 782 threads x 512
// serial iters; fix: 8-way split + fold into scan.
//
// Pipeline (built once, reused by both layers):
//   CS chunk_sort:  block i counting-sorts its 12500-edge chunk by bucket in LDS;
//                   writes srt CHUNK-MAJOR (own window) + histg/segst tables.
//   T  tot8:        part[k][j] = sum of 32-chunk slice k of histg[.][j]
//   S  scan1024:    tot[j] = sum_k part[k][j]; exclusive scan -> bucket_base
//   BS bucket_sort: per bucket: scan count row, copy segments into LDS stage,
//                   col-histogram -> ptr/dinv, scatter to srt2 CSR slots.
// Per layer:
//   proj:   p[i] = pack_bf16x2((h[i] @ W) * dinv[i])   (p overlays dead srt)
//   gather: 2 lanes/node (uint4 = 8 feats each), unroll-8, fp32 accum,
//           fused h@V+b+relu, float4 stores.

#define WC 128          // bucket width (cols)
#define LG2WC 7
#define MAXB 1024       // padded bucket count (supports n up to 131072)
#define NBC 256         // partition chunks
#define SCAP 8192       // bucket_sort LDS stage capacity

__device__ inline unsigned bf16rte(float x) {
    unsigned u = __float_as_uint(x);
    return (u + 0x7FFFu + ((u >> 16) & 1u)) >> 16;
}

// Block i: counting-sort its chunk by bucket; chunk-major output.
__global__ void chunk_sort(const int* __restrict__ row, const int* __restrict__ col,
                           int* __restrict__ srt, int* __restrict__ histg,
                           int* __restrict__ segst, int E, int B, int chunkE) {
    __shared__ int hist[MAXB];
    __shared__ int cur[MAXB];
    __shared__ int tsum[256];
    int i = blockIdx.x, t = threadIdx.x;
    for (int j = t; j < MAXB; j += 256) hist[j] = 0;
    __syncthreads();
    int lo = i * chunkE, hi = lo + chunkE; if (hi > E) hi = E;
    for (int e = lo + t; e < hi; e += 256)
        atomicAdd(&hist[col[e] >> LG2WC], 1);   // plain load: keep chunk L2-hot
    __syncthreads();
    // exclusive scan hist[0..MAXB) -> cur (4 elems/thread + Hillis-Steele)
    int b0 = t * 4;
    int c0 = hist[b0], c1 = hist[b0 + 1], c2 = hist[b0 + 2], c3 = hist[b0 + 3];
    int s = c0 + c1 + c2 + c3;
    tsum[t] = s;
    __syncthreads();
    for (int off = 1; off < 256; off <<= 1) {
        int u = 0;
        if (t >= off) u = tsum[t - off];
        __syncthreads();
        if (t >= off) tsum[t] += u;
        __syncthreads();
    }
    int run = tsum[t] - s;
    cur[b0] = run; run += c0;
    cur[b0 + 1] = run; run += c1;
    cur[b0 + 2] = run; run += c2;
    cur[b0 + 3] = run;
    __syncthreads();
    // write tables (chunk-major, coalesced)
    for (int j = t; j < B; j += 256) {
        histg[(size_t)i * B + j] = hist[j];
        segst[(size_t)i * B + j] = cur[j];
    }
    __syncthreads();
    // pass 2: re-read (L2-hot) and scatter into own window [lo,hi)
    for (int e = lo + t; e < hi; e += 256) {
        int c = col[e];
        int r = row[e];
        int pos = lo + atomicAdd(&cur[c >> LG2WC], 1);   // LDS cursor
        srt[pos] = ((c & (WC - 1)) << 17) | r;           // row<2^17, lcol bits 17..23
    }
}

// part[k*B+j] = sum_{i in slice k} histg[i*B+j]; 8 slices of 32 chunks.
__global__ void tot8_kernel(const int* __restrict__ histg, int* __restrict__ part, int B) {
    int idx = blockIdx.x * blockDim.x + threadIdx.x;
    if (idx >= 8 * B) return;
    int k = idx / B, j = idx - k * B;   // consecutive threads -> consecutive j (coalesced)
    int s = 0;
    for (int i = k * 32; i < k * 32 + 32; i++) s += histg[(size_t)i * B + j];
    part[(size_t)k * B + j] = s;
}

__global__ void scan1024_kernel(const int* __restrict__ part, int* __restrict__ base, int B) {
    __shared__ int s[1024];
    int t = threadIdx.x;
    int v = 0;
    if (t < B) {
#pragma unroll
        for (int k = 0; k < 8; k++) v += part[(size_t)k * B + t];
    }
    s[t] = v;
    __syncthreads();
    for (int off = 1; off < 1024; off <<= 1) {
        int u = 0;
        if (t >= off) u = s[t - off];
        __syncthreads();
        if (t >= off) s[t] += u;
        __syncthreads();
    }
    if (t < B) base[t] = s[t] - v;  // exclusive
}

// Per bucket: gather 256 segments (LDS stage), col-sort -> srt2 CSR + ptr + dinv.
__global__ void bucket_sort(const int* __restrict__ srt, const int* __restrict__ histg,
                            const int* __restrict__ segst, const int* __restrict__ bbase,
                            int* __restrict__ ptr, int* __restrict__ srt2,
                            float* __restrict__ dinv, int E, int n, int B, int chunkE) {
    __shared__ int hrow[NBC];
    __shared__ int srow[NBC];
    __shared__ int spref[NBC];
    __shared__ int stage[SCAP];
    __shared__ int tsum[256];
    __shared__ int cnt[WC], colb[WC], ccur[WC];
    __shared__ int Ssh;
    int j = blockIdx.x, t = threadIdx.x;
    // NBC == 256 == blockDim: one table entry per thread
    hrow[t] = histg[(size_t)t * B + j];   // strided, L2-resident table
    srow[t] = segst[(size_t)t * B + j];
    if (t < WC) cnt[t] = 0;
    __syncthreads();
    // exclusive scan hrow[0..256) -> spref
    int v = hrow[t];
    tsum[t] = v;
    __syncthreads();
    for (int off = 1; off < 256; off <<= 1) {
        int u = 0;
        if (t >= off) u = tsum[t - off];
        __syncthreads();
        if (t >= off) tsum[t] += u;
        __syncthreads();
    }
    spref[t] = tsum[t] - v;
    if (t == 255) Ssh = tsum[255];
    __syncthreads();
    int S = Ssh;                 // bucket size (block-uniform)
    int gbase = bbase[j];
    bool fits = (S <= SCAP);     // uniform branch
    if (fits) {
        int src = t * chunkE + srow[t];
        int dst = spref[t];
        int len = hrow[t];
        for (int q = 0; q < len; q++) stage[dst + q] = srt[src + q];
        __syncthreads();
        for (int e = t; e < S; e += 256) atomicAdd(&cnt[stage[e] >> 17], 1);
    } else {
        int src = t * chunkE + srow[t];
        int len = hrow[t];
        for (int q = 0; q < len; q++) atomicAdd(&cnt[srt[src + q] >> 17], 1);
    }
    __syncthreads();
    // scan cnt[0..128) -> colb; emit ptr/dinv; init cursors
    if (t < WC) colb[t] = cnt[t];
    __syncthreads();
    for (int off = 1; off < WC; off <<= 1) {
        int u = 0;
        if (t >= off && t < WC) u = colb[t - off];
        __syncthreads();
        if (t >= off && t < WC) colb[t] += u;
        __syncthreads();
    }
    if (t < WC) {
        int excl = colb[t] - cnt[t];
        int c = j * WC + t;
        ccur[t] = gbase + excl;
        if (c < n) {
            ptr[c] = gbase + excl;
            dinv[c] = cnt[t] > 0 ? rsqrtf((float)cnt[t]) : 0.0f;
        }
    }
    if (j == B - 1 && t == 0) ptr[n] = E;
    __syncthreads();
    if (fits) {
        for (int e = t; e < S; e += 256) {
            int pk = stage[e];
            int pos = atomicAdd(&ccur[pk >> 17], 1);
            srt2[pos] = pk & 0x1FFFF;
        }
    } else {
        int src = t * chunkE + srow[t];
        int len = hrow[t];
        for (int q = 0; q < len; q++) {
            int pk = srt[src + q];
            int pos = atomicAdd(&ccur[pk >> 17], 1);
            srt2[pos] = pk & 0x1FFFF;
        }
    }
}

// p row = 8 uint32 (16 bf16) = 32 B.
template <int FI>
__global__ void proj_kernel(const float* __restrict__ hin, const float* __restrict__ W,
                            const float* __restrict__ dinv, unsigned* __restrict__ p, int n) {
    __shared__ float sW[FI * 16];
    for (int t = threadIdx.x; t < FI * 16; t += blockDim.x) sW[t] = W[t];
    __syncthreads();
    int i = blockIdx.x * blockDim.x + threadIdx.x;
    if (i >= n) return;
    float hi[FI];
    const float4* hr = (const float4*)(hin + (size_t)i * FI);
#pragma unroll
    for (int k = 0; k < FI / 4; k++) {
        float4 v = hr[k];
        hi[4 * k] = v.x; hi[4 * k + 1] = v.y; hi[4 * k + 2] = v.z; hi[4 * k + 3] = v.w;
    }
    float di = dinv[i];
    float outv[16];
#pragma unroll
    for (int f = 0; f < 16; f++) {
        float s = 0.0f;
#pragma unroll
        for (int k = 0; k < FI; k++) s += hi[k] * sW[k * 16 + f];
        outv[f] = s * di;
    }
    uint4 u0, u1;
    u0.x = bf16rte(outv[0])  | (bf16rte(outv[1])  << 16);
    u0.y = bf16rte(outv[2])  | (bf16rte(outv[3])  << 16);
    u0.z = bf16rte(outv[4])  | (bf16rte(outv[5])  << 16);
    u0.w = bf16rte(outv[6])  | (bf16rte(outv[7])  << 16);
    u1.x = bf16rte(outv[8])  | (bf16rte(outv[9])  << 16);
    u1.y = bf16rte(outv[10]) | (bf16rte(outv[11]) << 16);
    u1.z = bf16rte(outv[12]) | (bf16rte(outv[13]) << 16);
    u1.w = bf16rte(outv[14]) | (bf16rte(outv[15]) << 16);
    uint4* pr = (uint4*)(p + (size_t)i * 8);
    pr[0] = u0;
    pr[1] = u1;
}

// 2 lanes per node; lane hb owns features 8*hb..8*hb+7 (one uint4 = 16B of the
// 32B packed p row per edge). fp32 accumulate; fused h@V+b+relu; float4 stores.
// hin/out may alias (layer 2): both lanes of a node read only their OWN h row;
// wave-lockstep => reads precede stores.
template <int FI>
__global__ __launch_bounds__(256, 4)
void gather_finish_kernel(const int* __restrict__ ptr, const int* __restrict__ srt2,
                          const uint4* __restrict__ p, const float* hin,
                          const float* __restrict__ V, const float* __restrict__ b,
                          const float* __restrict__ dinv, float* out, int n) {
    __shared__ float sV[FI * 16];
    __shared__ float sb[16];
    for (int t = threadIdx.x; t < FI * 16; t += blockDim.x) sV[t] = V[t];
    if (threadIdx.x < 16) sb[threadIdx.x] = b[threadIdx.x];
    __syncthreads();
    int g = blockIdx.x * (blockDim.x >> 1) + (threadIdx.x >> 1);
    int hb = threadIdx.x & 1;
    if (g >= n) return;
    int s0 = ptr[g], s1 = ptr[g + 1];
    const uint4* pb = p + hb;           // lane's half: p[(size_t)r*2 + hb]
    float a0 = 0, a1 = 0, a2 = 0, a3 = 0, a4 = 0, a5 = 0, a6 = 0, a7 = 0;
    int e = s0;
    for (; e + 8 <= s1; e += 8) {
        int r[8];
#pragma unroll
        for (int q = 0; q < 8; q++) r[q] = __builtin_nontemporal_load(srt2 + e + q);
        uint4 u[8];
#pragma unroll
        for (int q = 0; q < 8; q++) u[q] = pb[(size_t)r[q] * 2];
#pragma unroll
        for (int q = 0; q < 8; q++) {
            a0 += __uint_as_float(u[q].x << 16);
            a1 += __uint_as_float(u[q].x & 0xFFFF0000u);
            a2 += __uint_as_float(u[q].y << 16);
            a3 += __uint_as_float(u[q].y & 0xFFFF0000u);
            a4 += __uint_as_float(u[q].z << 16);
            a5 += __uint_as_float(u[q].z & 0xFFFF0000u);
            a6 += __uint_as_float(u[q].w << 16);
            a7 += __uint_as_float(u[q].w & 0xFFFF0000u);
        }
    }
    for (; e < s1; e++) {
        uint4 u = pb[(size_t)__builtin_nontemporal_load(srt2 + e) * 2];
        a0 += __uint_as_float(u.x << 16);
        a1 += __uint_as_float(u.x & 0xFFFF0000u);
        a2 += __uint_as_float(u.y << 16);
        a3 += __uint_as_float(u.y & 0xFFFF0000u);
        a4 += __uint_as_float(u.z << 16);
        a5 += __uint_as_float(u.z & 0xFFFF0000u);
        a6 += __uint_as_float(u.w << 16);
        a7 += __uint_as_float(u.w & 0xFFFF0000u);
    }
    // fused finish: h@V + b + dinv*agg, relu (features f0..f0+7)
    int f0 = hb * 8;
    float hi[FI];
    const float4* h4 = (const float4*)(hin + (size_t)g * FI);
#pragma unroll
    for (int k = 0; k < FI / 4; k++) {
        float4 v = h4[k];
        hi[4 * k] = v.x; hi[4 * k + 1] = v.y; hi[4 * k + 2] = v.z; hi[4 * k + 3] = v.w;
    }
    float hv[8] = {0, 0, 0, 0, 0, 0, 0, 0};
#pragma unroll
    for (int k = 0; k < FI; k++) {
        float hk = hi[k];
#pragma unroll
        for (int q = 0; q < 8; q++) hv[q] += hk * sV[k * 16 + f0 + q];
    }
    float di = dinv[g];
    float rr[8] = {a0, a1, a2, a3, a4, a5, a6, a7};
#pragma unroll
    for (int q = 0; q < 8; q++) {
        float r_ = sb[f0 + q] + di * rr[q] + hv[q];
        rr[q] = r_ > 0.0f ? r_ : 0.0f;
    }
    float4* o4 = (float4*)(out + (size_t)g * 16 + f0);
    o4[0] = make_float4(rr[0], rr[1], rr[2], rr[3]);
    o4[1] = make_float4(rr[4], rr[5], rr[6], rr[7]);
}

extern "C" void kernel_launch(void* const* d_in, const int* in_sizes, int n_in,
                              void* d_out, int out_size, void* d_ws, size_t ws_size,
                              hipStream_t stream) {
    const float* x  = (const float*)d_in[0];
    const int*   ei = (const int*)d_in[1];
    const float* W1 = (const float*)d_in[2];
    const float* V1 = (const float*)d_in[3];
    const float* b1 = (const float*)d_in[4];
    const float* W2 = (const float*)d_in[5];
    const float* V2 = (const float*)d_in[6];
    const float* b2 = (const float*)d_in[7];

    const int n = in_sizes[0] / 8;       // 100000 nodes
    const int E = in_sizes[1] / 2;       // 3200000 edges
    const int* row = ei;                 // edge_index[0]
    const int* col = ei + E;             // edge_index[1]

    const int B = (n + WC - 1) / WC;     // 782 buckets
    const int chunkE = (E + NBC - 1) / NBC;  // 12500

    auto align = [](size_t v) { return (v + 255) / 256 * 256; };
    char* ws = (char*)d_ws;
    size_t off = 0;
    float* dinv  = (float*)(ws + off); off += align((size_t)n * 4);
    int*   ptr   = (int*)(ws + off);   off += align((size_t)(n + 1) * 4);
    int*   histg = (int*)(ws + off);   off += align((size_t)NBC * B * 4);
    int*   segst = (int*)(ws + off);   off += align((size_t)NBC * B * 4);
    int*   part  = (int*)(ws + off);   off += align((size_t)8 * B * 4);
    int*   bbase = (int*)(ws + off);   off += align((size_t)B * 4);
    // srt is dead after bucket_sort; proj writes packed p over the same region.
    int*      srt = (int*)(ws + off);
    unsigned* p   = (unsigned*)(ws + off); off += align((size_t)E * 4);  // E*4 >= n*8*4
    int*      srt2 = (int*)(ws + off);     off += align((size_t)E * 4);
    float* out = (float*)d_out;
    // ~28 MB total

    const int bs = 256;
    const int gbN = (n + bs - 1) / bs;
    const int gbG = (n * 2 + bs - 1) / bs;   // gather: 2 lanes per node

    // CSR build (no global atomics; all writes single-writer L2-resident windows)
    chunk_sort<<<NBC, bs, 0, stream>>>(row, col, srt, histg, segst, E, B, chunkE);
    tot8_kernel<<<(8 * B + bs - 1) / bs, bs, 0, stream>>>(histg, part, B);
    scan1024_kernel<<<1, 1024, 0, stream>>>(part, bbase, B);
    bucket_sort<<<B, bs, 0, stream>>>(srt, histg, segst, bbase, ptr, srt2, dinv, E, n, B, chunkE);

    // Layer 1 (FI=8): x -> d_out   (proj overwrites srt region with p — srt is dead)
    proj_kernel<8><<<gbN, bs, 0, stream>>>(x, W1, dinv, p, n);
    gather_finish_kernel<8><<<gbG, bs, 0, stream>>>(ptr, srt2, (const uint4*)p, x, V1, b1, dinv, out, n);

    // Layer 2 (FI=16): d_out -> d_out
    proj_kernel<16><<<gbN, bs, 0, stream>>>(out, W2, dinv, p, n);
    gather_finish_kernel<16><<<gbG, bs, 0, stream>>>(ptr, srt2, (const uint4*)p, out, V2, b2, dinv, out, n);
}

// Round 10
// 152.858 us; speedup vs baseline: 5.1955x; 1.0732x over previous
//
#include <hip/hip_runtime.h>

// ARMA GNN (T=1,K=1) x2 layers on MI355X — chunk-major partition + bf16-packed
// wide-load gather.
//
// Round-9 lesson: chunk_sort was at 9% occupancy (256 blocks = 1 block/CU = 4
// waves/CU) -> latency-bound at 50us. Fix: 1024-thread blocks (16 waves/CU),
// same NBC=256 chunk structure (bucket_sort needs >=64B segments, round-8).
//
// Pipeline (built once, reused by both layers):
//   CS chunk_sort:  block i (1024 thr) counting-sorts its 12500-edge chunk by
//                   bucket in LDS; writes srt CHUNK-MAJOR + histg/segst tables.
//   T  tot8:        part[k][j] = sum of 32-chunk slice k of histg[.][j]
//   S  scan1024:    tot[j] = sum_k part[k][j]; exclusive scan -> bucket_base
//   BS bucket_sort: per bucket: scan count row, copy segments into LDS stage,
//                   col-histogram -> ptr/dinv, scatter to srt2 CSR slots.
// Per layer:
//   proj:   p[i] = pack_bf16x2((h[i] @ W) * dinv[i])   (p overlays dead srt)
//   gather: 2 lanes/node (uint4 = 8 feats each), unroll-8, fp32 accum,
//           fused h@V+b+relu, float4 stores.

#define WC 128          // bucket width (cols)
#define LG2WC 7
#define MAXB 1024       // padded bucket count (supports n up to 131072)
#define NBC 256         // partition chunks
#define SCAP 8192       // bucket_sort LDS stage capacity

__device__ inline unsigned bf16rte(float x) {
    unsigned u = __float_as_uint(x);
    return (u + 0x7FFFu + ((u >> 16) & 1u)) >> 16;
}

// Block i (1024 threads): counting-sort its chunk by bucket; chunk-major output.
__global__ __launch_bounds__(1024)
void chunk_sort(const int* __restrict__ row, const int* __restrict__ col,
                int* __restrict__ srt, int* __restrict__ histg,
                int* __restrict__ segst, int E, int B, int chunkE) {
    __shared__ int hist[MAXB];
    __shared__ int cur[MAXB];
    __shared__ int tsum[MAXB];
    int i = blockIdx.x, t = threadIdx.x;
    hist[t] = 0;
    __syncthreads();
    int lo = i * chunkE, hi = lo + chunkE; if (hi > E) hi = E;
    for (int e = lo + t; e < hi; e += 1024)
        atomicAdd(&hist[col[e] >> LG2WC], 1);   // plain load: keep chunk L2-hot
    __syncthreads();
    // exclusive scan hist[0..1024) -> cur (1 elem/thread Hillis-Steele)
    int v = hist[t];
    tsum[t] = v;
    __syncthreads();
    for (int off = 1; off < 1024; off <<= 1) {
        int u = 0;
        if (t >= off) u = tsum[t - off];
        __syncthreads();
        if (t >= off) tsum[t] += u;
        __syncthreads();
    }
    cur[t] = tsum[t] - v;
    __syncthreads();
    // write tables (chunk-major, coalesced)
    if (t < B) {
        histg[(size_t)i * B + t] = hist[t];
        segst[(size_t)i * B + t] = cur[t];
    }
    __syncthreads();
    // pass 2: re-read (L2-hot) and scatter into own window [lo,hi)
    for (int e = lo + t; e < hi; e += 1024) {
        int c = col[e];
        int r = row[e];
        int pos = lo + atomicAdd(&cur[c >> LG2WC], 1);   // LDS cursor
        srt[pos] = ((c & (WC - 1)) << 17) | r;           // row<2^17, lcol bits 17..23
    }
}

// part[k*B+j] = sum_{i in slice k} histg[i*B+j]; 8 slices of 32 chunks.
__global__ void tot8_kernel(const int* __restrict__ histg, int* __restrict__ part, int B) {
    int idx = blockIdx.x * blockDim.x + threadIdx.x;
    if (idx >= 8 * B) return;
    int k = idx / B, j = idx - k * B;   // consecutive threads -> consecutive j (coalesced)
    int s = 0;
    for (int i = k * 32; i < k * 32 + 32; i++) s += histg[(size_t)i * B + j];
    part[(size_t)k * B + j] = s;
}

__global__ void scan1024_kernel(const int* __restrict__ part, int* __restrict__ base, int B) {
    __shared__ int s[1024];
    int t = threadIdx.x;
    int v = 0;
    if (t < B) {
#pragma unroll
        for (int k = 0; k < 8; k++) v += part[(size_t)k * B + t];
    }
    s[t] = v;
    __syncthreads();
    for (int off = 1; off < 1024; off <<= 1) {
        int u = 0;
        if (t >= off) u = s[t - off];
        __syncthreads();
        if (t >= off) s[t] += u;
        __syncthreads();
    }
    if (t < B) base[t] = s[t] - v;  // exclusive
}

// Per bucket: gather 256 segments (LDS stage), col-sort -> srt2 CSR + ptr + dinv.
__global__ void bucket_sort(const int* __restrict__ srt, const int* __restrict__ histg,
                            const int* __restrict__ segst, const int* __restrict__ bbase,
                            int* __restrict__ ptr, int* __restrict__ srt2,
                            float* __restrict__ dinv, int E, int n, int B, int chunkE) {
    __shared__ int hrow[NBC];
    __shared__ int srow[NBC];
    __shared__ int spref[NBC];
    __shared__ int stage[SCAP];
    __shared__ int tsum[256];
    __shared__ int cnt[WC], colb[WC], ccur[WC];
    __shared__ int Ssh;
    int j = blockIdx.x, t = threadIdx.x;
    // NBC == 256 == blockDim: one table entry per thread
    hrow[t] = histg[(size_t)t * B + j];   // strided, L2-resident table
    srow[t] = segst[(size_t)t * B + j];
    if (t < WC) cnt[t] = 0;
    __syncthreads();
    // exclusive scan hrow[0..256) -> spref
    int v = hrow[t];
    tsum[t] = v;
    __syncthreads();
    for (int off = 1; off < 256; off <<= 1) {
        int u = 0;
        if (t >= off) u = tsum[t - off];
        __syncthreads();
        if (t >= off) tsum[t] += u;
        __syncthreads();
    }
    spref[t] = tsum[t] - v;
    if (t == 255) Ssh = tsum[255];
    __syncthreads();
    int S = Ssh;                 // bucket size (block-uniform)
    int gbase = bbase[j];
    bool fits = (S <= SCAP);     // uniform branch
    if (fits) {
        int src = t * chunkE + srow[t];
        int dst = spref[t];
        int len = hrow[t];
        for (int q = 0; q < len; q++) stage[dst + q] = srt[src + q];
        __syncthreads();
        for (int e = t; e < S; e += 256) atomicAdd(&cnt[stage[e] >> 17], 1);
    } else {
        int src = t * chunkE + srow[t];
        int len = hrow[t];
        for (int q = 0; q < len; q++) atomicAdd(&cnt[srt[src + q] >> 17], 1);
    }
    __syncthreads();
    // scan cnt[0..128) -> colb; emit ptr/dinv; init cursors
    if (t < WC) colb[t] = cnt[t];
    __syncthreads();
    for (int off = 1; off < WC; off <<= 1) {
        int u = 0;
        if (t >= off && t < WC) u = colb[t - off];
        __syncthreads();
        if (t >= off && t < WC) colb[t] += u;
        __syncthreads();
    }
    if (t < WC) {
        int excl = colb[t] - cnt[t];
        int c = j * WC + t;
        ccur[t] = gbase + excl;
        if (c < n) {
            ptr[c] = gbase + excl;
            dinv[c] = cnt[t] > 0 ? rsqrtf((float)cnt[t]) : 0.0f;
        }
    }
    if (j == B - 1 && t == 0) ptr[n] = E;
    __syncthreads();
    if (fits) {
        for (int e = t; e < S; e += 256) {
            int pk = stage[e];
            int pos = atomicAdd(&ccur[pk >> 17], 1);
            srt2[pos] = pk & 0x1FFFF;
        }
    } else {
        int src = t * chunkE + srow[t];
        int len = hrow[t];
        for (int q = 0; q < len; q++) {
            int pk = srt[src + q];
            int pos = atomicAdd(&ccur[pk >> 17], 1);
            srt2[pos] = pk & 0x1FFFF;
        }
    }
}

// p row = 8 uint32 (16 bf16) = 32 B.
template <int FI>
__global__ void proj_kernel(const float* __restrict__ hin, const float* __restrict__ W,
                            const float* __restrict__ dinv, unsigned* __restrict__ p, int n) {
    __shared__ float sW[FI * 16];
    for (int t = threadIdx.x; t < FI * 16; t += blockDim.x) sW[t] = W[t];
    __syncthreads();
    int i = blockIdx.x * blockDim.x + threadIdx.x;
    if (i >= n) return;
    float hi[FI];
    const float4* hr = (const float4*)(hin + (size_t)i * FI);
#pragma unroll
    for (int k = 0; k < FI / 4; k++) {
        float4 v = hr[k];
        hi[4 * k] = v.x; hi[4 * k + 1] = v.y; hi[4 * k + 2] = v.z; hi[4 * k + 3] = v.w;
    }
    float di = dinv[i];
    float outv[16];
#pragma unroll
    for (int f = 0; f < 16; f++) {
        float s = 0.0f;
#pragma unroll
        for (int k = 0; k < FI; k++) s += hi[k] * sW[k * 16 + f];
        outv[f] = s * di;
    }
    uint4 u0, u1;
    u0.x = bf16rte(outv[0])  | (bf16rte(outv[1])  << 16);
    u0.y = bf16rte(outv[2])  | (bf16rte(outv[3])  << 16);
    u0.z = bf16rte(outv[4])  | (bf16rte(outv[5])  << 16);
    u0.w = bf16rte(outv[6])  | (bf16rte(outv[7])  << 16);
    u1.x = bf16rte(outv[8])  | (bf16rte(outv[9])  << 16);
    u1.y = bf16rte(outv[10]) | (bf16rte(outv[11]) << 16);
    u1.z = bf16rte(outv[12]) | (bf16rte(outv[13]) << 16);
    u1.w = bf16rte(outv[14]) | (bf16rte(outv[15]) << 16);
    uint4* pr = (uint4*)(p + (size_t)i * 8);
    pr[0] = u0;
    pr[1] = u1;
}

// 2 lanes per node; lane hb owns features 8*hb..8*hb+7 (one uint4 = 16B of the
// 32B packed p row per edge). fp32 accumulate; fused h@V+b+relu; float4 stores.
// hin/out may alias (layer 2): both lanes of a node read only their OWN h row;
// wave-lockstep => reads precede stores.
template <int FI>
__global__ __launch_bounds__(256, 4)
void gather_finish_kernel(const int* __restrict__ ptr, const int* __restrict__ srt2,
                          const uint4* __restrict__ p, const float* hin,
                          const float* __restrict__ V, const float* __restrict__ b,
                          const float* __restrict__ dinv, float* out, int n) {
    __shared__ float sV[FI * 16];
    __shared__ float sb[16];
    for (int t = threadIdx.x; t < FI * 16; t += blockDim.x) sV[t] = V[t];
    if (threadIdx.x < 16) sb[threadIdx.x] = b[threadIdx.x];
    __syncthreads();
    int g = blockIdx.x * (blockDim.x >> 1) + (threadIdx.x >> 1);
    int hb = threadIdx.x & 1;
    if (g >= n) return;
    int s0 = ptr[g], s1 = ptr[g + 1];
    const uint4* pb = p + hb;           // lane's half: p[(size_t)r*2 + hb]
    float a0 = 0, a1 = 0, a2 = 0, a3 = 0, a4 = 0, a5 = 0, a6 = 0, a7 = 0;
    int e = s0;
    for (; e + 8 <= s1; e += 8) {
        int r[8];
#pragma unroll
        for (int q = 0; q < 8; q++) r[q] = __builtin_nontemporal_load(srt2 + e + q);
        uint4 u[8];
#pragma unroll
        for (int q = 0; q < 8; q++) u[q] = pb[(size_t)r[q] * 2];
#pragma unroll
        for (int q = 0; q < 8; q++) {
            a0 += __uint_as_float(u[q].x << 16);
            a1 += __uint_as_float(u[q].x & 0xFFFF0000u);
            a2 += __uint_as_float(u[q].y << 16);
            a3 += __uint_as_float(u[q].y & 0xFFFF0000u);
            a4 += __uint_as_float(u[q].z << 16);
            a5 += __uint_as_float(u[q].z & 0xFFFF0000u);
            a6 += __uint_as_float(u[q].w << 16);
            a7 += __uint_as_float(u[q].w & 0xFFFF0000u);
        }
    }
    for (; e < s1; e++) {
        uint4 u = pb[(size_t)__builtin_nontemporal_load(srt2 + e) * 2];
        a0 += __uint_as_float(u.x << 16);
        a1 += __uint_as_float(u.x & 0xFFFF0000u);
        a2 += __uint_as_float(u.y << 16);
        a3 += __uint_as_float(u.y & 0xFFFF0000u);
        a4 += __uint_as_float(u.z << 16);
        a5 += __uint_as_float(u.z & 0xFFFF0000u);
        a6 += __uint_as_float(u.w << 16);
        a7 += __uint_as_float(u.w & 0xFFFF0000u);
    }
    // fused finish: h@V + b + dinv*agg, relu (features f0..f0+7)
    int f0 = hb * 8;
    float hi[FI];
    const float4* h4 = (const float4*)(hin + (size_t)g * FI);
#pragma unroll
    for (int k = 0; k < FI / 4; k++) {
        float4 v = h4[k];
        hi[4 * k] = v.x; hi[4 * k + 1] = v.y; hi[4 * k + 2] = v.z; hi[4 * k + 3] = v.w;
    }
    float hv[8] = {0, 0, 0, 0, 0, 0, 0, 0};
#pragma unroll
    for (int k = 0; k < FI; k++) {
        float hk = hi[k];
#pragma unroll
        for (int q = 0; q < 8; q++) hv[q] += hk * sV[k * 16 + f0 + q];
    }
    float di = dinv[g];
    float rr[8] = {a0, a1, a2, a3, a4, a5, a6, a7};
#pragma unroll
    for (int q = 0; q < 8; q++) {
        float r_ = sb[f0 + q] + di * rr[q] + hv[q];
        rr[q] = r_ > 0.0f ? r_ : 0.0f;
    }
    float4* o4 = (float4*)(out + (size_t)g * 16 + f0);
    o4[0] = make_float4(rr[0], rr[1], rr[2], rr[3]);
    o4[1] = make_float4(rr[4], rr[5], rr[6], rr[7]);
}

extern "C" void kernel_launch(void* const* d_in, const int* in_sizes, int n_in,
                              void* d_out, int out_size, void* d_ws, size_t ws_size,
                              hipStream_t stream) {
    const float* x  = (const float*)d_in[0];
    const int*   ei = (const int*)d_in[1];
    const float* W1 = (const float*)d_in[2];
    const float* V1 = (const float*)d_in[3];
    const float* b1 = (const float*)d_in[4];
    const float* W2 = (const float*)d_in[5];
    const float* V2 = (const float*)d_in[6];
    const float* b2 = (const float*)d_in[7];

    const int n = in_sizes[0] / 8;       // 100000 nodes
    const int E = in_sizes[1] / 2;       // 3200000 edges
    const int* row = ei;                 // edge_index[0]
    const int* col = ei + E;             // edge_index[1]

    const int B = (n + WC - 1) / WC;     // 782 buckets
    const int chunkE = (E + NBC - 1) / NBC;  // 12500

    auto align = [](size_t v) { return (v + 255) / 256 * 256; };
    char* ws = (char*)d_ws;
    size_t off = 0;
    float* dinv  = (float*)(ws + off); off += align((size_t)n * 4);
    int*   ptr   = (int*)(ws + off);   off += align((size_t)(n + 1) * 4);
    int*   histg = (int*)(ws + off);   off += align((size_t)NBC * B * 4);
    int*   segst = (int*)(ws + off);   off += align((size_t)NBC * B * 4);
    int*   part  = (int*)(ws + off);   off += align((size_t)8 * B * 4);
    int*   bbase = (int*)(ws + off);   off += align((size_t)B * 4);
    // srt is dead after bucket_sort; proj writes packed p over the same region.
    int*      srt = (int*)(ws + off);
    unsigned* p   = (unsigned*)(ws + off); off += align((size_t)E * 4);  // E*4 >= n*8*4
    int*      srt2 = (int*)(ws + off);     off += align((size_t)E * 4);
    float* out = (float*)d_out;
    // ~28 MB total

    const int bs = 256;
    const int gbN = (n + bs - 1) / bs;
    const int gbG = (n * 2 + bs - 1) / bs;   // gather: 2 lanes per node

    // CSR build (no global atomics; all writes single-writer L2-resident windows)
    chunk_sort<<<NBC, 1024, 0, stream>>>(row, col, srt, histg, segst, E, B, chunkE);
    tot8_kernel<<<(8 * B + bs - 1) / bs, bs, 0, stream>>>(histg, part, B);
    scan1024_kernel<<<1, 1024, 0, stream>>>(part, bbase, B);
    bucket_sort<<<B, bs, 0, stream>>>(srt, histg, segst, bbase, ptr, srt2, dinv, E, n, B, chunkE);

    // Layer 1 (FI=8): x -> d_out   (proj overwrites srt region with p — srt is dead)
    proj_kernel<8><<<gbN, bs, 0, stream>>>(x, W1, dinv, p, n);
    gather_finish_kernel<8><<<gbG, bs, 0, stream>>>(ptr, srt2, (const uint4*)p, x, V1, b1, dinv, out, n);

    // Layer 2 (FI=16): d_out -> d_out
    proj_kernel<16><<<gbN, bs, 0, stream>>>(out, W2, dinv, p, n);
    gather_finish_kernel<16><<<gbG, bs, 0, stream>>>(ptr, srt2, (const uint4*)p, out, V2, b2, dinv, out, n);
}

// Round 11
// 150.183 us; speedup vs baseline: 5.2880x; 1.0178x over previous
//
#include <hip/hip_runtime.h>

// ARMA GNN (T=1,K=1) x2 layers on MI355X — chunk-major partition + bf16-packed
// 4-lane-split gather.
//
// Round-10 lesson: gather is (chain-length x latency)/TLP bound, NOT load-slot
// bound (8-lane@56%occ == 2-lane@20%occ == ~43us). Fix: 4 lanes/node =
// 2 feature-halves x 2 edge-halves -> chain halved, threads doubled (24 w/CU),
// divergence reduced; partial sums merged with shfl_xor. Per-edge address work
// unchanged (2 uint4 lane-loads per edge row = structural minimum for 32B).
//
// Pipeline (built once, reused by both layers):
//   CS chunk_sort:  block i (1024 thr) counting-sorts its 12500-edge chunk by
//                   bucket in LDS; writes srt CHUNK-MAJOR + histg/segst tables.
//   T  tot8:        part[k][j] = sum of 32-chunk slice k of histg[.][j]
//   S  scan1024:    tot[j] = sum_k part[k][j]; exclusive scan -> bucket_base
//   BS bucket_sort: per bucket: scan count row, copy segments into LDS stage,
//                   col-histogram -> ptr/dinv, scatter to srt2 CSR slots.
// Per layer:
//   proj:   p[i] = pack_bf16x2((h[i] @ W) * dinv[i])   (p overlays dead srt)
//   gather: 4 lanes/node (hb=feat-half, sh=edge-half), unroll-8, fp32 accum,
//           shfl_xor combine, fused h@V+b+relu, float4 stores.

#define WC 128          // bucket width (cols)
#define LG2WC 7
#define MAXB 1024       // padded bucket count (supports n up to 131072)
#define NBC 256         // partition chunks
#define SCAP 8192       // bucket_sort LDS stage capacity

__device__ inline unsigned bf16rte(float x) {
    unsigned u = __float_as_uint(x);
    return (u + 0x7FFFu + ((u >> 16) & 1u)) >> 16;
}

// Block i (1024 threads): counting-sort its chunk by bucket; chunk-major output.
__global__ __launch_bounds__(1024)
void chunk_sort(const int* __restrict__ row, const int* __restrict__ col,
                int* __restrict__ srt, int* __restrict__ histg,
                int* __restrict__ segst, int E, int B, int chunkE) {
    __shared__ int hist[MAXB];
    __shared__ int cur[MAXB];
    __shared__ int tsum[MAXB];
    int i = blockIdx.x, t = threadIdx.x;
    hist[t] = 0;
    __syncthreads();
    int lo = i * chunkE, hi = lo + chunkE; if (hi > E) hi = E;
    for (int e = lo + t; e < hi; e += 1024)
        atomicAdd(&hist[col[e] >> LG2WC], 1);   // plain load: keep chunk L2-hot
    __syncthreads();
    // exclusive scan hist[0..1024) -> cur (1 elem/thread Hillis-Steele)
    int v = hist[t];
    tsum[t] = v;
    __syncthreads();
    for (int off = 1; off < 1024; off <<= 1) {
        int u = 0;
        if (t >= off) u = tsum[t - off];
        __syncthreads();
        if (t >= off) tsum[t] += u;
        __syncthreads();
    }
    cur[t] = tsum[t] - v;
    __syncthreads();
    // write tables (chunk-major, coalesced)
    if (t < B) {
        histg[(size_t)i * B + t] = hist[t];
        segst[(size_t)i * B + t] = cur[t];
    }
    __syncthreads();
    // pass 2: re-read (L2-hot) and scatter into own window [lo,hi)
    for (int e = lo + t; e < hi; e += 1024) {
        int c = col[e];
        int r = row[e];
        int pos = lo + atomicAdd(&cur[c >> LG2WC], 1);   // LDS cursor
        srt[pos] = ((c & (WC - 1)) << 17) | r;           // row<2^17, lcol bits 17..23
    }
}

// part[k*B+j] = sum_{i in slice k} histg[i*B+j]; 8 slices of 32 chunks.
__global__ void tot8_kernel(const int* __restrict__ histg, int* __restrict__ part, int B) {
    int idx = blockIdx.x * blockDim.x + threadIdx.x;
    if (idx >= 8 * B) return;
    int k = idx / B, j = idx - k * B;   // consecutive threads -> consecutive j (coalesced)
    int s = 0;
    for (int i = k * 32; i < k * 32 + 32; i++) s += histg[(size_t)i * B + j];
    part[(size_t)k * B + j] = s;
}

__global__ void scan1024_kernel(const int* __restrict__ part, int* __restrict__ base, int B) {
    __shared__ int s[1024];
    int t = threadIdx.x;
    int v = 0;
    if (t < B) {
#pragma unroll
        for (int k = 0; k < 8; k++) v += part[(size_t)k * B + t];
    }
    s[t] = v;
    __syncthreads();
    for (int off = 1; off < 1024; off <<= 1) {
        int u = 0;
        if (t >= off) u = s[t - off];
        __syncthreads();
        if (t >= off) s[t] += u;
        __syncthreads();
    }
    if (t < B) base[t] = s[t] - v;  // exclusive
}

// Per bucket: gather 256 segments (LDS stage), col-sort -> srt2 CSR + ptr + dinv.
__global__ void bucket_sort(const int* __restrict__ srt, const int* __restrict__ histg,
                            const int* __restrict__ segst, const int* __restrict__ bbase,
                            int* __restrict__ ptr, int* __restrict__ srt2,
                            float* __restrict__ dinv, int E, int n, int B, int chunkE) {
    __shared__ int hrow[NBC];
    __shared__ int srow[NBC];
    __shared__ int spref[NBC];
    __shared__ int stage[SCAP];
    __shared__ int tsum[256];
    __shared__ int cnt[WC], colb[WC], ccur[WC];
    __shared__ int Ssh;
    int j = blockIdx.x, t = threadIdx.x;
    // NBC == 256 == blockDim: one table entry per thread
    hrow[t] = histg[(size_t)t * B + j];   // strided, L2-resident table
    srow[t] = segst[(size_t)t * B + j];
    if (t < WC) cnt[t] = 0;
    __syncthreads();
    // exclusive scan hrow[0..256) -> spref
    int v = hrow[t];
    tsum[t] = v;
    __syncthreads();
    for (int off = 1; off < 256; off <<= 1) {
        int u = 0;
        if (t >= off) u = tsum[t - off];
        __syncthreads();
        if (t >= off) tsum[t] += u;
        __syncthreads();
    }
    spref[t] = tsum[t] - v;
    if (t == 255) Ssh = tsum[255];
    __syncthreads();
    int S = Ssh;                 // bucket size (block-uniform)
    int gbase = bbase[j];
    bool fits = (S <= SCAP);     // uniform branch
    if (fits) {
        int src = t * chunkE + srow[t];
        int dst = spref[t];
        int len = hrow[t];
        for (int q = 0; q < len; q++) stage[dst + q] = srt[src + q];
        __syncthreads();
        for (int e = t; e < S; e += 256) atomicAdd(&cnt[stage[e] >> 17], 1);
    } else {
        int src = t * chunkE + srow[t];
        int len = hrow[t];
        for (int q = 0; q < len; q++) atomicAdd(&cnt[srt[src + q] >> 17], 1);
    }
    __syncthreads();
    // scan cnt[0..128) -> colb; emit ptr/dinv; init cursors
    if (t < WC) colb[t] = cnt[t];
    __syncthreads();
    for (int off = 1; off < WC; off <<= 1) {
        int u = 0;
        if (t >= off && t < WC) u = colb[t - off];
        __syncthreads();
        if (t >= off && t < WC) colb[t] += u;
        __syncthreads();
    }
    if (t < WC) {
        int excl = colb[t] - cnt[t];
        int c = j * WC + t;
        ccur[t] = gbase + excl;
        if (c < n) {
            ptr[c] = gbase + excl;
            dinv[c] = cnt[t] > 0 ? rsqrtf((float)cnt[t]) : 0.0f;
        }
    }
    if (j == B - 1 && t == 0) ptr[n] = E;
    __syncthreads();
    if (fits) {
        for (int e = t; e < S; e += 256) {
            int pk = stage[e];
            int pos = atomicAdd(&ccur[pk >> 17], 1);
            srt2[pos] = pk & 0x1FFFF;
        }
    } else {
        int src = t * chunkE + srow[t];
        int len = hrow[t];
        for (int q = 0; q < len; q++) {
            int pk = srt[src + q];
            int pos = atomicAdd(&ccur[pk >> 17], 1);
            srt2[pos] = pk & 0x1FFFF;
        }
    }
}

// p row = 8 uint32 (16 bf16) = 32 B.
template <int FI>
__global__ void proj_kernel(const float* __restrict__ hin, const float* __restrict__ W,
                            const float* __restrict__ dinv, unsigned* __restrict__ p, int n) {
    __shared__ float sW[FI * 16];
    for (int t = threadIdx.x; t < FI * 16; t += blockDim.x) sW[t] = W[t];
    __syncthreads();
    int i = blockIdx.x * blockDim.x + threadIdx.x;
    if (i >= n) return;
    float hi[FI];
    const float4* hr = (const float4*)(hin + (size_t)i * FI);
#pragma unroll
    for (int k = 0; k < FI / 4; k++) {
        float4 v = hr[k];
        hi[4 * k] = v.x; hi[4 * k + 1] = v.y; hi[4 * k + 2] = v.z; hi[4 * k + 3] = v.w;
    }
    float di = dinv[i];
    float outv[16];
#pragma unroll
    for (int f = 0; f < 16; f++) {
        float s = 0.0f;
#pragma unroll
        for (int k = 0; k < FI; k++) s += hi[k] * sW[k * 16 + f];
        outv[f] = s * di;
    }
    uint4 u0, u1;
    u0.x = bf16rte(outv[0])  | (bf16rte(outv[1])  << 16);
    u0.y = bf16rte(outv[2])  | (bf16rte(outv[3])  << 16);
    u0.z = bf16rte(outv[4])  | (bf16rte(outv[5])  << 16);
    u0.w = bf16rte(outv[6])  | (bf16rte(outv[7])  << 16);
    u1.x = bf16rte(outv[8])  | (bf16rte(outv[9])  << 16);
    u1.y = bf16rte(outv[10]) | (bf16rte(outv[11]) << 16);
    u1.z = bf16rte(outv[12]) | (bf16rte(outv[13]) << 16);
    u1.w = bf16rte(outv[14]) | (bf16rte(outv[15]) << 16);
    uint4* pr = (uint4*)(p + (size_t)i * 8);
    pr[0] = u0;
    pr[1] = u1;
}

// 4 lanes per node: hb = lane&1 (feature half, uint4 = 8 feats), sh = (lane>>1)&1
// (edge half). Each lane walks half the node's edge list; halves merge via
// shfl_xor(.,2). fp32 accumulate; fused h@V+b+relu on sh==0; float4 stores.
// hin/out may alias (layer 2): a node's h row is read only by its own lanes and
// all reads precede the stores in wave program order.
template <int FI>
__global__ __launch_bounds__(256, 4)
void gather_finish_kernel(const int* __restrict__ ptr, const int* __restrict__ srt2,
                          const uint4* __restrict__ p, const float* hin,
                          const float* __restrict__ V, const float* __restrict__ b,
                          const float* __restrict__ dinv, float* out, int n) {
    __shared__ float sV[FI * 16];
    __shared__ float sb[16];
    for (int t = threadIdx.x; t < FI * 16; t += blockDim.x) sV[t] = V[t];
    if (threadIdx.x < 16) sb[threadIdx.x] = b[threadIdx.x];
    __syncthreads();
    int g = blockIdx.x * (blockDim.x >> 2) + (threadIdx.x >> 2);
    int hb = threadIdx.x & 1;
    int sh = (threadIdx.x >> 1) & 1;
    if (g >= n) return;
    int s0 = ptr[g], s1 = ptr[g + 1];
    int mid = (s0 + s1) >> 1;
    int e0 = sh ? mid : s0;
    int e1 = sh ? s1 : mid;
    const uint4* pb = p + hb;           // lane's half: p[(size_t)r*2 + hb]
    float a0 = 0, a1 = 0, a2 = 0, a3 = 0, a4 = 0, a5 = 0, a6 = 0, a7 = 0;
    int e = e0;
    for (; e + 8 <= e1; e += 8) {
        int r[8];
#pragma unroll
        for (int q = 0; q < 8; q++) r[q] = __builtin_nontemporal_load(srt2 + e + q);
        uint4 u[8];
#pragma unroll
        for (int q = 0; q < 8; q++) u[q] = pb[(size_t)r[q] * 2];
#pragma unroll
        for (int q = 0; q < 8; q++) {
            a0 += __uint_as_float(u[q].x << 16);
            a1 += __uint_as_float(u[q].x & 0xFFFF0000u);
            a2 += __uint_as_float(u[q].y << 16);
            a3 += __uint_as_float(u[q].y & 0xFFFF0000u);
            a4 += __uint_as_float(u[q].z << 16);
            a5 += __uint_as_float(u[q].z & 0xFFFF0000u);
            a6 += __uint_as_float(u[q].w << 16);
            a7 += __uint_as_float(u[q].w & 0xFFFF0000u);
        }
    }
    for (; e < e1; e++) {
        uint4 u = pb[(size_t)__builtin_nontemporal_load(srt2 + e) * 2];
        a0 += __uint_as_float(u.x << 16);
        a1 += __uint_as_float(u.x & 0xFFFF0000u);
        a2 += __uint_as_float(u.y << 16);
        a3 += __uint_as_float(u.y & 0xFFFF0000u);
        a4 += __uint_as_float(u.z << 16);
        a5 += __uint_as_float(u.z & 0xFFFF0000u);
        a6 += __uint_as_float(u.w << 16);
        a7 += __uint_as_float(u.w & 0xFFFF0000u);
    }
    // merge edge halves (lane ^ 2 is the other sh, same hb, same node)
    a0 += __shfl_xor(a0, 2);
    a1 += __shfl_xor(a1, 2);
    a2 += __shfl_xor(a2, 2);
    a3 += __shfl_xor(a3, 2);
    a4 += __shfl_xor(a4, 2);
    a5 += __shfl_xor(a5, 2);
    a6 += __shfl_xor(a6, 2);
    a7 += __shfl_xor(a7, 2);
    if (sh != 0) return;
    // fused finish: h@V + b + dinv*agg, relu (features f0..f0+7)
    int f0 = hb * 8;
    float hi[FI];
    const float4* h4 = (const float4*)(hin + (size_t)g * FI);
#pragma unroll
    for (int k = 0; k < FI / 4; k++) {
        float4 v = h4[k];
        hi[4 * k] = v.x; hi[4 * k + 1] = v.y; hi[4 * k + 2] = v.z; hi[4 * k + 3] = v.w;
    }
    float hv[8] = {0, 0, 0, 0, 0, 0, 0, 0};
#pragma unroll
    for (int k = 0; k < FI; k++) {
        float hk = hi[k];
#pragma unroll
        for (int q = 0; q < 8; q++) hv[q] += hk * sV[k * 16 + f0 + q];
    }
    float di = dinv[g];
    float rr[8] = {a0, a1, a2, a3, a4, a5, a6, a7};
#pragma unroll
    for (int q = 0; q < 8; q++) {
        float r_ = sb[f0 + q] + di * rr[q] + hv[q];
        rr[q] = r_ > 0.0f ? r_ : 0.0f;
    }
    float4* o4 = (float4*)(out + (size_t)g * 16 + f0);
    o4[0] = make_float4(rr[0], rr[1], rr[2], rr[3]);
    o4[1] = make_float4(rr[4], rr[5], rr[6], rr[7]);
}

extern "C" void kernel_launch(void* const* d_in, const int* in_sizes, int n_in,
                              void* d_out, int out_size, void* d_ws, size_t ws_size,
                              hipStream_t stream) {
    const float* x  = (const float*)d_in[0];
    const int*   ei = (const int*)d_in[1];
    const float* W1 = (const float*)d_in[2];
    const float* V1 = (const float*)d_in[3];
    const float* b1 = (const float*)d_in[4];
    const float* W2 = (const float*)d_in[5];
    const float* V2 = (const float*)d_in[6];
    const float* b2 = (const float*)d_in[7];

    const int n = in_sizes[0] / 8;       // 100000 nodes
    const int E = in_sizes[1] / 2;       // 3200000 edges
    const int* row = ei;                 // edge_index[0]
    const int* col = ei + E;             // edge_index[1]

    const int B = (n + WC - 1) / WC;     // 782 buckets
    const int chunkE = (E + NBC - 1) / NBC;  // 12500

    auto align = [](size_t v) { return (v + 255) / 256 * 256; };
    char* ws = (char*)d_ws;
    size_t off = 0;
    float* dinv  = (float*)(ws + off); off += align((size_t)n * 4);
    int*   ptr   = (int*)(ws + off);   off += align((size_t)(n + 1) * 4);
    int*   histg = (int*)(ws + off);   off += align((size_t)NBC * B * 4);
    int*   segst = (int*)(ws + off);   off += align((size_t)NBC * B * 4);
    int*   part  = (int*)(ws + off);   off += align((size_t)8 * B * 4);
    int*   bbase = (int*)(ws + off);   off += align((size_t)B * 4);
    // srt is dead after bucket_sort; proj writes packed p over the same region.
    int*      srt = (int*)(ws + off);
    unsigned* p   = (unsigned*)(ws + off); off += align((size_t)E * 4);  // E*4 >= n*8*4
    int*      srt2 = (int*)(ws + off);     off += align((size_t)E * 4);
    float* out = (float*)d_out;
    // ~28 MB total

    const int bs = 256;
    const int gbN = (n + bs - 1) / bs;
    const int gbG = (n * 4 + bs - 1) / bs;   // gather: 4 lanes per node

    // CSR build (no global atomics; all writes single-writer L2-resident windows)
    chunk_sort<<<NBC, 1024, 0, stream>>>(row, col, srt, histg, segst, E, B, chunkE);
    tot8_kernel<<<(8 * B + bs - 1) / bs, bs, 0, stream>>>(histg, part, B);
    scan1024_kernel<<<1, 1024, 0, stream>>>(part, bbase, B);
    bucket_sort<<<B, bs, 0, stream>>>(srt, histg, segst, bbase, ptr, srt2, dinv, E, n, B, chunkE);

    // Layer 1 (FI=8): x -> d_out   (proj overwrites srt region with p — srt is dead)
    proj_kernel<8><<<gbN, bs, 0, stream>>>(x, W1, dinv, p, n);
    gather_finish_kernel<8><<<gbG, bs, 0, stream>>>(ptr, srt2, (const uint4*)p, x, V1, b1, dinv, out, n);

    // Layer 2 (FI=16): d_out -> d_out
    proj_kernel<16><<<gbN, bs, 0, stream>>>(out, W2, dinv, p, n);
    gather_finish_kernel<16><<<gbG, bs, 0, stream>>>(ptr, srt2, (const uint4*)p, out, V2, b2, dinv, out, n);
}

// Round 12
// 150.136 us; speedup vs baseline: 5.2897x; 1.0003x over previous
//
#include <hip/hip_runtime.h>

// ARMA GNN (T=1,K=1) x2 layers on MI355X — chunk-major partition + bf16-packed
// 4-lane-split gather with predicated (tail-free) inner loop.
//
// Round-11 lesson: gather pinned at ~44us across 8/2/4-lane decompositions and
// 20->~75% occupancy -> bound by the SERIAL scalar remainder loop (up to 7
// dependent srt2->p chains @ ~500cy each, expected ~3.5 = 1750cy > main loop).
// Fix: predicated full-width unroll-8 blocks (clamped index, cndmask-zeroed
// values) -> no serial tail; every edge is in a parallel-issue block.
//
// Pipeline (built once, reused by both layers):
//   CS chunk_sort:  block i (1024 thr) counting-sorts its 12500-edge chunk by
//                   bucket in LDS; writes srt CHUNK-MAJOR + histg/segst tables.
//   T  tot8:        part[k][j] = sum of 32-chunk slice k of histg[.][j]
//   S  scan1024:    tot[j] = sum_k part[k][j]; exclusive scan -> bucket_base
//   BS bucket_sort: per bucket: scan count row, copy segments into LDS stage,
//                   col-histogram -> ptr/dinv, scatter to srt2 CSR slots.
// Per layer:
//   proj:   p[i] = pack_bf16x2((h[i] @ W) * dinv[i])   (p overlays dead srt)
//   gather: 4 lanes/node (hb=feat-half, sh=edge-half), predicated unroll-8,
//           fp32 accum, shfl_xor combine, fused h@V+b+relu, float4 stores.

#define WC 128          // bucket width (cols)
#define LG2WC 7
#define MAXB 1024       // padded bucket count (supports n up to 131072)
#define NBC 256         // partition chunks
#define SCAP 8192       // bucket_sort LDS stage capacity

typedef unsigned uintv4 __attribute__((ext_vector_type(4)));

__device__ inline unsigned bf16rte(float x) {
    unsigned u = __float_as_uint(x);
    return (u + 0x7FFFu + ((u >> 16) & 1u)) >> 16;
}

// Block i (1024 threads): counting-sort its chunk by bucket; chunk-major output.
__global__ __launch_bounds__(1024)
void chunk_sort(const int* __restrict__ row, const int* __restrict__ col,
                int* __restrict__ srt, int* __restrict__ histg,
                int* __restrict__ segst, int E, int B, int chunkE) {
    __shared__ int hist[MAXB];
    __shared__ int cur[MAXB];
    __shared__ int tsum[MAXB];
    int i = blockIdx.x, t = threadIdx.x;
    hist[t] = 0;
    __syncthreads();
    int lo = i * chunkE, hi = lo + chunkE; if (hi > E) hi = E;
    for (int e = lo + t; e < hi; e += 1024)
        atomicAdd(&hist[col[e] >> LG2WC], 1);   // plain load: keep chunk L2-hot
    __syncthreads();
    // exclusive scan hist[0..1024) -> cur (1 elem/thread Hillis-Steele)
    int v = hist[t];
    tsum[t] = v;
    __syncthreads();
    for (int off = 1; off < 1024; off <<= 1) {
        int u = 0;
        if (t >= off) u = tsum[t - off];
        __syncthreads();
        if (t >= off) tsum[t] += u;
        __syncthreads();
    }
    cur[t] = tsum[t] - v;
    __syncthreads();
    // write tables (chunk-major, coalesced)
    if (t < B) {
        histg[(size_t)i * B + t] = hist[t];
        segst[(size_t)i * B + t] = cur[t];
    }
    __syncthreads();
    // pass 2: re-read (L2-hot) and scatter into own window [lo,hi)
    for (int e = lo + t; e < hi; e += 1024) {
        int c = col[e];
        int r = row[e];
        int pos = lo + atomicAdd(&cur[c >> LG2WC], 1);   // LDS cursor
        srt[pos] = ((c & (WC - 1)) << 17) | r;           // row<2^17, lcol bits 17..23
    }
}

// part[k*B+j] = sum_{i in slice k} histg[i*B+j]; 8 slices of 32 chunks.
__global__ void tot8_kernel(const int* __restrict__ histg, int* __restrict__ part, int B) {
    int idx = blockIdx.x * blockDim.x + threadIdx.x;
    if (idx >= 8 * B) return;
    int k = idx / B, j = idx - k * B;   // consecutive threads -> consecutive j (coalesced)
    int s = 0;
    for (int i = k * 32; i < k * 32 + 32; i++) s += histg[(size_t)i * B + j];
    part[(size_t)k * B + j] = s;
}

__global__ void scan1024_kernel(const int* __restrict__ part, int* __restrict__ base, int B) {
    __shared__ int s[1024];
    int t = threadIdx.x;
    int v = 0;
    if (t < B) {
#pragma unroll
        for (int k = 0; k < 8; k++) v += part[(size_t)k * B + t];
    }
    s[t] = v;
    __syncthreads();
    for (int off = 1; off < 1024; off <<= 1) {
        int u = 0;
        if (t >= off) u = s[t - off];
        __syncthreads();
        if (t >= off) s[t] += u;
        __syncthreads();
    }
    if (t < B) base[t] = s[t] - v;  // exclusive
}

// Per bucket: gather 256 segments (LDS stage), col-sort -> srt2 CSR + ptr + dinv.
__global__ void bucket_sort(const int* __restrict__ srt, const int* __restrict__ histg,
                            const int* __restrict__ segst, const int* __restrict__ bbase,
                            int* __restrict__ ptr, int* __restrict__ srt2,
                            float* __restrict__ dinv, int E, int n, int B, int chunkE) {
    __shared__ int hrow[NBC];
    __shared__ int srow[NBC];
    __shared__ int spref[NBC];
    __shared__ int stage[SCAP];
    __shared__ int tsum[256];
    __shared__ int cnt[WC], colb[WC], ccur[WC];
    __shared__ int Ssh;
    int j = blockIdx.x, t = threadIdx.x;
    // NBC == 256 == blockDim: one table entry per thread
    hrow[t] = histg[(size_t)t * B + j];   // strided, L2-resident table
    srow[t] = segst[(size_t)t * B + j];
    if (t < WC) cnt[t] = 0;
    __syncthreads();
    // exclusive scan hrow[0..256) -> spref
    int v = hrow[t];
    tsum[t] = v;
    __syncthreads();
    for (int off = 1; off < 256; off <<= 1) {
        int u = 0;
        if (t >= off) u = tsum[t - off];
        __syncthreads();
        if (t >= off) tsum[t] += u;
        __syncthreads();
    }
    spref[t] = tsum[t] - v;
    if (t == 255) Ssh = tsum[255];
    __syncthreads();
    int S = Ssh;                 // bucket size (block-uniform)
    int gbase = bbase[j];
    bool fits = (S <= SCAP);     // uniform branch
    if (fits) {
        int src = t * chunkE + srow[t];
        int dst = spref[t];
        int len = hrow[t];
        for (int q = 0; q < len; q++) stage[dst + q] = srt[src + q];
        __syncthreads();
        for (int e = t; e < S; e += 256) atomicAdd(&cnt[stage[e] >> 17], 1);
    } else {
        int src = t * chunkE + srow[t];
        int len = hrow[t];
        for (int q = 0; q < len; q++) atomicAdd(&cnt[srt[src + q] >> 17], 1);
    }
    __syncthreads();
    // scan cnt[0..128) -> colb; emit ptr/dinv; init cursors
    if (t < WC) colb[t] = cnt[t];
    __syncthreads();
    for (int off = 1; off < WC; off <<= 1) {
        int u = 0;
        if (t >= off && t < WC) u = colb[t - off];
        __syncthreads();
        if (t >= off && t < WC) colb[t] += u;
        __syncthreads();
    }
    if (t < WC) {
        int excl = colb[t] - cnt[t];
        int c = j * WC + t;
        ccur[t] = gbase + excl;
        if (c < n) {
            ptr[c] = gbase + excl;
            dinv[c] = cnt[t] > 0 ? rsqrtf((float)cnt[t]) : 0.0f;
        }
    }
    if (j == B - 1 && t == 0) ptr[n] = E;
    __syncthreads();
    if (fits) {
        for (int e = t; e < S; e += 256) {
            int pk = stage[e];
            int pos = atomicAdd(&ccur[pk >> 17], 1);
            srt2[pos] = pk & 0x1FFFF;
        }
    } else {
        int src = t * chunkE + srow[t];
        int len = hrow[t];
        for (int q = 0; q < len; q++) {
            int pk = srt[src + q];
            int pos = atomicAdd(&ccur[pk >> 17], 1);
            srt2[pos] = pk & 0x1FFFF;
        }
    }
}

// p row = 8 uint32 (16 bf16) = 32 B.
template <int FI>
__global__ void proj_kernel(const float* __restrict__ hin, const float* __restrict__ W,
                            const float* __restrict__ dinv, unsigned* __restrict__ p, int n) {
    __shared__ float sW[FI * 16];
    for (int t = threadIdx.x; t < FI * 16; t += blockDim.x) sW[t] = W[t];
    __syncthreads();
    int i = blockIdx.x * blockDim.x + threadIdx.x;
    if (i >= n) return;
    float hi[FI];
    const float4* hr = (const float4*)(hin + (size_t)i * FI);
#pragma unroll
    for (int k = 0; k < FI / 4; k++) {
        float4 v = hr[k];
        hi[4 * k] = v.x; hi[4 * k + 1] = v.y; hi[4 * k + 2] = v.z; hi[4 * k + 3] = v.w;
    }
    float di = dinv[i];
    float outv[16];
#pragma unroll
    for (int f = 0; f < 16; f++) {
        float s = 0.0f;
#pragma unroll
        for (int k = 0; k < FI; k++) s += hi[k] * sW[k * 16 + f];
        outv[f] = s * di;
    }
    uint4 u0, u1;
    u0.x = bf16rte(outv[0])  | (bf16rte(outv[1])  << 16);
    u0.y = bf16rte(outv[2])  | (bf16rte(outv[3])  << 16);
    u0.z = bf16rte(outv[4])  | (bf16rte(outv[5])  << 16);
    u0.w = bf16rte(outv[6])  | (bf16rte(outv[7])  << 16);
    u1.x = bf16rte(outv[8])  | (bf16rte(outv[9])  << 16);
    u1.y = bf16rte(outv[10]) | (bf16rte(outv[11]) << 16);
    u1.z = bf16rte(outv[12]) | (bf16rte(outv[13]) << 16);
    u1.w = bf16rte(outv[14]) | (bf16rte(outv[15]) << 16);
    uint4* pr = (uint4*)(p + (size_t)i * 8);
    pr[0] = u0;
    pr[1] = u1;
}

// 4 lanes per node: hb = lane&1 (feature half, 16B of the 32B row), sh =
// (lane>>1)&1 (edge half). Predicated unroll-8: every block is full-width
// (clamped index, zeroed value) -> NO serial remainder tail. Halves merge via
// shfl_xor(.,2); fused h@V+b+relu on sh==0; float4 stores.
// hin/out may alias (layer 2): a node's h row is read only by its own lanes and
// all reads precede the stores in wave program order.
template <int FI>
__global__ __launch_bounds__(256, 4)
void gather_finish_kernel(const int* __restrict__ ptr, const int* __restrict__ srt2,
                          const uintv4* __restrict__ p, const float* hin,
                          const float* __restrict__ V, const float* __restrict__ b,
                          const float* __restrict__ dinv, float* out, int n) {
    __shared__ float sV[FI * 16];
    __shared__ float sb[16];
    for (int t = threadIdx.x; t < FI * 16; t += blockDim.x) sV[t] = V[t];
    if (threadIdx.x < 16) sb[threadIdx.x] = b[threadIdx.x];
    __syncthreads();
    int g = blockIdx.x * (blockDim.x >> 2) + (threadIdx.x >> 2);
    int hb = threadIdx.x & 1;
    int sh = (threadIdx.x >> 1) & 1;
    if (g >= n) return;
    int s0 = ptr[g], s1 = ptr[g + 1];
    int mid = (s0 + s1) >> 1;
    int e0 = sh ? mid : s0;
    int e1 = sh ? s1 : mid;
    const uintv4* pb = p + hb;          // lane's half: p[(size_t)r*2 + hb]
    float a0 = 0, a1 = 0, a2 = 0, a3 = 0, a4 = 0, a5 = 0, a6 = 0, a7 = 0;
    for (int e = e0; e < e1; e += 8) {
        int r[8];
#pragma unroll
        for (int q = 0; q < 8; q++) {
            int idx = e + q;
            r[q] = __builtin_nontemporal_load(srt2 + (idx < e1 ? idx : e1 - 1));
        }
        uintv4 u[8];
#pragma unroll
        for (int q = 0; q < 8; q++) u[q] = pb[(size_t)r[q] * 2];
#pragma unroll
        for (int q = 0; q < 8; q++) {
            if (e + q >= e1) u[q] = (uintv4)0;   // cndmask-zero: bf16 0 -> 0.0f
            a0 += __uint_as_float(u[q][0] << 16);
            a1 += __uint_as_float(u[q][0] & 0xFFFF0000u);
            a2 += __uint_as_float(u[q][1] << 16);
            a3 += __uint_as_float(u[q][1] & 0xFFFF0000u);
            a4 += __uint_as_float(u[q][2] << 16);
            a5 += __uint_as_float(u[q][2] & 0xFFFF0000u);
            a6 += __uint_as_float(u[q][3] << 16);
            a7 += __uint_as_float(u[q][3] & 0xFFFF0000u);
        }
    }
    // merge edge halves (lane ^ 2 is the other sh, same hb, same node)
    a0 += __shfl_xor(a0, 2);
    a1 += __shfl_xor(a1, 2);
    a2 += __shfl_xor(a2, 2);
    a3 += __shfl_xor(a3, 2);
    a4 += __shfl_xor(a4, 2);
    a5 += __shfl_xor(a5, 2);
    a6 += __shfl_xor(a6, 2);
    a7 += __shfl_xor(a7, 2);
    if (sh != 0) return;
    // fused finish: h@V + b + dinv*agg, relu (features f0..f0+7)
    int f0 = hb * 8;
    float hi[FI];
    const float4* h4 = (const float4*)(hin + (size_t)g * FI);
#pragma unroll
    for (int k = 0; k < FI / 4; k++) {
        float4 v = h4[k];
        hi[4 * k] = v.x; hi[4 * k + 1] = v.y; hi[4 * k + 2] = v.z; hi[4 * k + 3] = v.w;
    }
    float hv[8] = {0, 0, 0, 0, 0, 0, 0, 0};
#pragma unroll
    for (int k = 0; k < FI; k++) {
        float hk = hi[k];
#pragma unroll
        for (int q = 0; q < 8; q++) hv[q] += hk * sV[k * 16 + f0 + q];
    }
    float di = dinv[g];
    float rr[8] = {a0, a1, a2, a3, a4, a5, a6, a7};
#pragma unroll
    for (int q = 0; q < 8; q++) {
        float r_ = sb[f0 + q] + di * rr[q] + hv[q];
        rr[q] = r_ > 0.0f ? r_ : 0.0f;
    }
    float4* o4 = (float4*)(out + (size_t)g * 16 + f0);
    o4[0] = make_float4(rr[0], rr[1], rr[2], rr[3]);
    o4[1] = make_float4(rr[4], rr[5], rr[6], rr[7]);
}

extern "C" void kernel_launch(void* const* d_in, const int* in_sizes, int n_in,
                              void* d_out, int out_size, void* d_ws, size_t ws_size,
                              hipStream_t stream) {
    const float* x  = (const float*)d_in[0];
    const int*   ei = (const int*)d_in[1];
    const float* W1 = (const float*)d_in[2];
    const float* V1 = (const float*)d_in[3];
    const float* b1 = (const float*)d_in[4];
    const float* W2 = (const float*)d_in[5];
    const float* V2 = (const float*)d_in[6];
    const float* b2 = (const float*)d_in[7];

    const int n = in_sizes[0] / 8;       // 100000 nodes
    const int E = in_sizes[1] / 2;       // 3200000 edges
    const int* row = ei;                 // edge_index[0]
    const int* col = ei + E;             // edge_index[1]

    const int B = (n + WC - 1) / WC;     // 782 buckets
    const int chunkE = (E + NBC - 1) / NBC;  // 12500

    auto align = [](size_t v) { return (v + 255) / 256 * 256; };
    char* ws = (char*)d_ws;
    size_t off = 0;
    float* dinv  = (float*)(ws + off); off += align((size_t)n * 4);
    int*   ptr   = (int*)(ws + off);   off += align((size_t)(n + 1) * 4);
    int*   histg = (int*)(ws + off);   off += align((size_t)NBC * B * 4);
    int*   segst = (int*)(ws + off);   off += align((size_t)NBC * B * 4);
    int*   part  = (int*)(ws + off);   off += align((size_t)8 * B * 4);
    int*   bbase = (int*)(ws + off);   off += align((size_t)B * 4);
    // srt is dead after bucket_sort; proj writes packed p over the same region.
    int*      srt = (int*)(ws + off);
    unsigned* p   = (unsigned*)(ws + off); off += align((size_t)E * 4);  // E*4 >= n*8*4
    int*      srt2 = (int*)(ws + off);     off += align((size_t)E * 4);
    float* out = (float*)d_out;
    // ~28 MB total

    const int bs = 256;
    const int gbN = (n + bs - 1) / bs;
    const int gbG = (n * 4 + bs - 1) / bs;   // gather: 4 lanes per node

    // CSR build (no global atomics; all writes single-writer L2-resident windows)
    chunk_sort<<<NBC, 1024, 0, stream>>>(row, col, srt, histg, segst, E, B, chunkE);
    tot8_kernel<<<(8 * B + bs - 1) / bs, bs, 0, stream>>>(histg, part, B);
    scan1024_kernel<<<1, 1024, 0, stream>>>(part, bbase, B);
    bucket_sort<<<B, bs, 0, stream>>>(srt, histg, segst, bbase, ptr, srt2, dinv, E, n, B, chunkE);

    // Layer 1 (FI=8): x -> d_out   (proj overwrites srt region with p — srt is dead)
    proj_kernel<8><<<gbN, bs, 0, stream>>>(x, W1, dinv, p, n);
    gather_finish_kernel<8><<<gbG, bs, 0, stream>>>(ptr, srt2, (const uintv4*)p, x, V1, b1, dinv, out, n);

    // Layer 2 (FI=16): d_out -> d_out
    proj_kernel<16><<<gbN, bs, 0, stream>>>(out, W2, dinv, p, n);
    gather_finish_kernel<16><<<gbG, bs, 0, stream>>>(ptr, srt2, (const uintv4*)p, out, V2, b2, dinv, out, n);
}